// Round 6
// baseline (215.841 us; speedup 1.0000x reference)
//
#include <hip/hip_runtime.h>
#include <hip/hip_bf16.h>

#define IN_DIM 128
#define HID 64
#define BM 128
#define BK 32
#define SCAN_B 1024

// ---- proj1: [xW | xWr] = x @ [Wl1 | Wr1]  (N x 128) @ (128 x 128) ---------
// 8x8 acc, BK=32, conflict-free-by-construction LDS layouts:
//   a-reads: phase-broadcast (r = tx>>4)
//   b-reads: interleaved W layout (chunk c low -> 4c, high -> 64+4c)
__global__ __launch_bounds__(256) void proj1_kernel(
    const float* __restrict__ x, const float* __restrict__ Wl,
    const float* __restrict__ Wr, float* __restrict__ xW,
    float* __restrict__ xWr, int N) {
  __shared__ float xs[BK][BM + 1];  // [k][node], stride 129 (== 1 mod 32)
  __shared__ float ws[BK][132];     // [k][permuted col]
  const int tx = threadIdx.x;
  const int c = tx & 15;  // col group: logical cols c*8 .. c*8+7
  const int r = tx >> 4;  // node group: nodes r*8 .. r*8+7
  const int n0 = blockIdx.x * BM;

  // x staging: node ln = tx>>1 (0..127), k-offset lk = (tx&1)*16
  const int ln = tx >> 1;
  const int lk = (tx & 1) * 16;
  const int gnode = n0 + ln;
  // W staging: row wk = tx>>3 (0..31), w = tx&7 -> logical cols 16w..16w+15
  const int wk = tx >> 3;
  const int w = tx & 7;

  float acc[8][8];
#pragma unroll
  for (int i = 0; i < 8; ++i)
#pragma unroll
    for (int j = 0; j < 8; ++j) acc[i][j] = 0.f;

#pragma unroll 1
  for (int k0 = 0; k0 < IN_DIM; k0 += BK) {
    float4 xa0, xa1, xa2, xa3;
    if (gnode < N) {
      const float* xp = &x[(size_t)gnode * IN_DIM + k0 + lk];
      xa0 = *(const float4*)(xp);
      xa1 = *(const float4*)(xp + 4);
      xa2 = *(const float4*)(xp + 8);
      xa3 = *(const float4*)(xp + 12);
    } else {
      xa0 = xa1 = xa2 = xa3 = make_float4(0.f, 0.f, 0.f, 0.f);
    }
    const float* wbase = (w < 4) ? &Wl[(size_t)(k0 + wk) * HID + 16 * w]
                                 : &Wr[(size_t)(k0 + wk) * HID + 16 * w - 64];
    const float4 wv0 = *(const float4*)(wbase);
    const float4 wv1 = *(const float4*)(wbase + 4);
    const float4 wv2 = *(const float4*)(wbase + 8);
    const float4 wv3 = *(const float4*)(wbase + 12);

    xs[lk + 0][ln] = xa0.x;
    xs[lk + 1][ln] = xa0.y;
    xs[lk + 2][ln] = xa0.z;
    xs[lk + 3][ln] = xa0.w;
    xs[lk + 4][ln] = xa1.x;
    xs[lk + 5][ln] = xa1.y;
    xs[lk + 6][ln] = xa1.z;
    xs[lk + 7][ln] = xa1.w;
    xs[lk + 8][ln] = xa2.x;
    xs[lk + 9][ln] = xa2.y;
    xs[lk + 10][ln] = xa2.z;
    xs[lk + 11][ln] = xa2.w;
    xs[lk + 12][ln] = xa3.x;
    xs[lk + 13][ln] = xa3.y;
    xs[lk + 14][ln] = xa3.z;
    xs[lk + 15][ln] = xa3.w;
    // interleaved store: logical chunk 2w (cols 16w..16w+7) -> low at 8w,
    // high at 64+8w; chunk 2w+1 -> low at 8w+4, high at 64+8w+4.
    *(float4*)&ws[wk][8 * w] = wv0;
    *(float4*)&ws[wk][64 + 8 * w] = wv1;
    *(float4*)&ws[wk][8 * w + 4] = wv2;
    *(float4*)&ws[wk][64 + 8 * w + 4] = wv3;
    __syncthreads();
#pragma unroll
    for (int k = 0; k < BK; ++k) {
      float a[8], b[8];
      *(float4*)&a[0] = *(const float4*)&xs[k][r * 8];      // broadcast/phase
      *(float4*)&a[4] = *(const float4*)&xs[k][r * 8 + 4];  // broadcast/phase
      *(float4*)&b[0] = *(const float4*)&ws[k][c * 4];       // contiguous
      *(float4*)&b[4] = *(const float4*)&ws[k][64 + c * 4];  // contiguous
#pragma unroll
      for (int i = 0; i < 8; ++i)
#pragma unroll
        for (int j = 0; j < 8; ++j) acc[i][j] += a[i] * b[j];
    }
    __syncthreads();
  }
#pragma unroll
  for (int i = 0; i < 8; ++i) {
    const int n = n0 + r * 8 + i;
    if (n < N) {
      float* dst = (c < 8) ? &xW[(size_t)n * HID + c * 8]
                           : &xWr[(size_t)n * HID + (c - 8) * 8];
      *(float4*)&dst[0] = *(float4*)&acc[i][0];
      *(float4*)&dst[4] = *(float4*)&acc[i][4];
    }
  }
}

// ---- CSR build ------------------------------------------------------------
__global__ __launch_bounds__(256) void count_kernel(const int* __restrict__ ei,
                                                    int* __restrict__ deg_i,
                                                    int E) {
  const int e = blockIdx.x * blockDim.x + threadIdx.x;
  if (e < E) atomicAdd(&deg_i[ei[E + e]], 1);
}

__global__ __launch_bounds__(SCAN_B) void scan1_kernel(
    const int* __restrict__ in, int* __restrict__ incl, int* __restrict__ bsum,
    int n) {
  __shared__ int s[SCAN_B];
  const int t = threadIdx.x;
  const int i = blockIdx.x * SCAN_B + t;
  int v = (i < n) ? in[i] : 0;
  s[t] = v;
  for (int off = 1; off < SCAN_B; off <<= 1) {
    __syncthreads();
    const int a = (t >= off) ? s[t - off] : 0;
    __syncthreads();
    s[t] += a;
  }
  if (i < n) incl[i] = s[t];
  if (t == SCAN_B - 1) bsum[blockIdx.x] = s[t];
}

__global__ __launch_bounds__(SCAN_B) void scan2_kernel(
    const int* __restrict__ bsum, int* __restrict__ boff, int nb) {
  __shared__ int s[SCAN_B];
  const int t = threadIdx.x;
  const int v = (t < nb) ? bsum[t] : 0;
  s[t] = v;
  for (int off = 1; off < SCAN_B; off <<= 1) {
    __syncthreads();
    const int a = (t >= off) ? s[t - off] : 0;
    __syncthreads();
    s[t] += a;
  }
  if (t < nb) boff[t] = s[t] - v;  // exclusive
}

__global__ __launch_bounds__(256) void scan3_kernel(
    const int* __restrict__ incl, const int* __restrict__ deg_i,
    const int* __restrict__ boff, int* __restrict__ row_off,
    int* __restrict__ cursor, int n) {
  const int i = blockIdx.x * blockDim.x + threadIdx.x;
  if (i < n) {
    const int st = incl[i] - deg_i[i] + boff[i >> 10];
    row_off[i] = st;
    cursor[i] = st;
  }
}

__global__ __launch_bounds__(256) void fill_kernel(const int* __restrict__ ei,
                                                   int* __restrict__ cursor,
                                                   int* __restrict__ csr_src,
                                                   int E) {
  const int e = blockIdx.x * blockDim.x + threadIdx.x;
  if (e < E) {
    const int s = ei[e];
    const int d = ei[E + e];
    const int pos = atomicAdd(&cursor[d], 1);
    csr_src[pos] = s;
  }
}

// ---- gather1: agg = sum_j xW[src]; h = relu(agg/deg + xWr + b1);
//      pl = h @ Wl2, pr = h @ Wr2  (all fused, wave per node) ---------------
__global__ __launch_bounds__(256) void gather1_kernel(
    const int* __restrict__ row_off, const int* __restrict__ deg_i,
    const int* __restrict__ csr_src, const float* __restrict__ xW,
    const float* __restrict__ xWr, const float* __restrict__ b1,
    const float* __restrict__ Wl2, const float* __restrict__ Wr2,
    float* __restrict__ pl, float* __restrict__ pr, int N) {
  const int lane = threadIdx.x & 63;
  const float wl0 = Wl2[lane * 3 + 0], wl1 = Wl2[lane * 3 + 1],
              wl2v = Wl2[lane * 3 + 2];
  const float wr0 = Wr2[lane * 3 + 0], wr1 = Wr2[lane * 3 + 1],
              wr2v = Wr2[lane * 3 + 2];
  const float bb = b1[lane];
  const int wave = (blockIdx.x * blockDim.x + threadIdx.x) >> 6;
  const int nwaves = (gridDim.x * blockDim.x) >> 6;
  for (int n = wave; n < N; n += nwaves) {
    const int start = row_off[n];
    const int dg = deg_i[n];
    float a0 = 0.f, a1 = 0.f, a2 = 0.f, a3 = 0.f;
    int r = 0;
    for (; r + 3 < dg; r += 4) {
      const int s0 = csr_src[start + r];
      const int s1 = csr_src[start + r + 1];
      const int s2 = csr_src[start + r + 2];
      const int s3 = csr_src[start + r + 3];
      a0 += xW[(size_t)s0 * HID + lane];
      a1 += xW[(size_t)s1 * HID + lane];
      a2 += xW[(size_t)s2 * HID + lane];
      a3 += xW[(size_t)s3 * HID + lane];
    }
    for (; r < dg; ++r) a0 += xW[(size_t)csr_src[start + r] * HID + lane];
    const float dinv = 1.0f / fmaxf((float)dg, 1.0f);
    const float hv = fmaxf(
        ((a0 + a1) + (a2 + a3)) * dinv + xWr[(size_t)n * HID + lane] + bb,
        0.0f);
    float v0 = hv * wl0, v1 = hv * wl1, v2 = hv * wl2v;
    float v3 = hv * wr0, v4 = hv * wr1, v5 = hv * wr2v;
#pragma unroll
    for (int off = 32; off >= 1; off >>= 1) {
      v0 += __shfl_down(v0, off);
      v1 += __shfl_down(v1, off);
      v2 += __shfl_down(v2, off);
      v3 += __shfl_down(v3, off);
      v4 += __shfl_down(v4, off);
      v5 += __shfl_down(v5, off);
    }
    if (lane == 0) {
      pl[(size_t)n * 3 + 0] = v0;
      pl[(size_t)n * 3 + 1] = v1;
      pl[(size_t)n * 3 + 2] = v2;
      pr[(size_t)n * 3 + 0] = v3;
      pr[(size_t)n * 3 + 1] = v4;
      pr[(size_t)n * 3 + 2] = v5;
    }
  }
}

// ---- final: gather pl over neighbors, log_softmax -------------------------
__global__ __launch_bounds__(256) void final_kernel(
    const int* __restrict__ row_off, const int* __restrict__ deg_i,
    const int* __restrict__ csr_src, const float* __restrict__ pl,
    const float* __restrict__ pr, const float* __restrict__ b2,
    float* __restrict__ out, int N) {
  const int stride = gridDim.x * blockDim.x;
  const float b20 = b2[0], b21 = b2[1], b22 = b2[2];
  for (int n = blockIdx.x * blockDim.x + threadIdx.x; n < N; n += stride) {
    const int start = row_off[n];
    const int dg = deg_i[n];
    float s0 = 0.f, s1 = 0.f, s2 = 0.f;
    for (int r = 0; r < dg; ++r) {
      const int s = csr_src[start + r];
      s0 += pl[(size_t)s * 3 + 0];
      s1 += pl[(size_t)s * 3 + 1];
      s2 += pl[(size_t)s * 3 + 2];
    }
    const float dinv = 1.0f / fmaxf((float)dg, 1.0f);
    const float v0 = s0 * dinv + pr[(size_t)n * 3 + 0] + b20;
    const float v1 = s1 * dinv + pr[(size_t)n * 3 + 1] + b21;
    const float v2 = s2 * dinv + pr[(size_t)n * 3 + 2] + b22;
    const float m = fmaxf(fmaxf(v0, v1), v2);
    const float e0 = __expf(v0 - m), e1 = __expf(v1 - m), e2 = __expf(v2 - m);
    const float lse = __logf(e0 + e1 + e2);
    out[(size_t)n * 3 + 0] = v0 - m - lse;
    out[(size_t)n * 3 + 1] = v1 - m - lse;
    out[(size_t)n * 3 + 2] = v2 - m - lse;
  }
}

extern "C" void kernel_launch(void* const* d_in, const int* in_sizes, int n_in,
                              void* d_out, int out_size, void* d_ws,
                              size_t ws_size, hipStream_t stream) {
  const float* x = (const float*)d_in[0];
  const int* ei = (const int*)d_in[1];  // int32 (JAX x64 disabled)
  const float* Wl1 = (const float*)d_in[2];
  const float* Wr1 = (const float*)d_in[3];
  const float* b1 = (const float*)d_in[4];
  const float* Wl2 = (const float*)d_in[5];
  const float* Wr2 = (const float*)d_in[6];
  const float* b2 = (const float*)d_in[7];
  float* out = (float*)d_out;

  const int N = in_sizes[0] / IN_DIM;
  const int E = in_sizes[1] / 2;
  const int nb1 = (N + SCAN_B - 1) / SCAN_B;

  int* wsI = (int*)d_ws;
  int* deg_i = wsI;              // [N]
  int* row_off = deg_i + N;      // [N]
  int* cursor = row_off + N;     // [N]
  int* incl = cursor + N;        // [N]
  int* bsum = incl + N;          // [SCAN_B]
  int* boff = bsum + SCAN_B;     // [SCAN_B]
  int* csr_src = boff + SCAN_B;  // [E]
  float* xW = (float*)(csr_src + E);  // [N*64]
  float* xWr = xW + (size_t)N * HID;  // [N*64]
  float* pl = xWr + (size_t)N * HID;  // [N*3]
  float* pr = pl + (size_t)N * 3;     // [N*3]

  hipMemsetAsync(deg_i, 0, (size_t)N * sizeof(int), stream);

  proj1_kernel<<<(N + BM - 1) / BM, 256, 0, stream>>>(x, Wl1, Wr1, xW, xWr, N);
  count_kernel<<<(E + 255) / 256, 256, 0, stream>>>(ei, deg_i, E);
  scan1_kernel<<<nb1, SCAN_B, 0, stream>>>(deg_i, incl, bsum, N);
  scan2_kernel<<<1, SCAN_B, 0, stream>>>(bsum, boff, nb1);
  scan3_kernel<<<(N + 255) / 256, 256, 0, stream>>>(incl, deg_i, boff, row_off,
                                                    cursor, N);
  fill_kernel<<<(E + 255) / 256, 256, 0, stream>>>(ei, cursor, csr_src, E);
  gather1_kernel<<<2048, 256, 0, stream>>>(row_off, deg_i, csr_src, xW, xWr,
                                           b1, Wl2, Wr2, pl, pr, N);
  final_kernel<<<(N + 255) / 256, 256, 0, stream>>>(row_off, deg_i, csr_src,
                                                    pl, pr, b2, out, N);
}

// Round 7
// 203.054 us; speedup vs baseline: 1.0630x; 1.0630x over previous
//
#include <hip/hip_runtime.h>
#include <hip/hip_bf16.h>

#define IN_DIM 128
#define HID 64
#define BM 64
#define BK 32
#define SCAN_B 1024

// ---- proj1: [xW | xWr] = x @ [Wl1 | Wr1]  (N x 128) @ (128 x 128) ---------
// 128 threads/block, BM=64, 8x8 per-thread tile.
//   xs: stride 72, odd k-half (k>=16) shifted +4 cols -> 2-way writes (free),
//       phase-broadcast reads (free).
//   ws: interleaved chunk layout (R6, proven ~400K conflicts).
__global__ __launch_bounds__(128) void proj1_kernel(
    const float* __restrict__ x, const float* __restrict__ Wl,
    const float* __restrict__ Wr, float* __restrict__ xW,
    float* __restrict__ xWr, int N) {
  __shared__ float xs[BK][BM + 8];  // stride 72
  __shared__ float ws[BK][132];     // interleaved W tile
  const int tx = threadIdx.x;  // 0..127
  const int c = tx & 15;       // col chunk: logical cols c*8 .. c*8+7
  const int r = tx >> 4;       // node group: nodes r*8 .. r*8+7 (0..7)
  const int n0 = blockIdx.x * BM;

  // x staging: node ln = tx>>1 (0..63), k-offset lk = (tx&1)*16
  const int ln = tx >> 1;
  const int lk = (tx & 1) * 16;
  const int xcol = ln + (lk ? 4 : 0);  // odd half shifted +4
  const int gnode = n0 + ln;
  // W staging: row wk = tx>>2 (0..31), w = tx&3 -> cols 32w..32w+31
  const int wk = tx >> 2;
  const int w = tx & 3;

  float acc[8][8];
#pragma unroll
  for (int i = 0; i < 8; ++i)
#pragma unroll
    for (int j = 0; j < 8; ++j) acc[i][j] = 0.f;

#pragma unroll 1
  for (int k0 = 0; k0 < IN_DIM; k0 += BK) {
    float4 xa0, xa1, xa2, xa3;
    if (gnode < N) {
      const float* xp = &x[(size_t)gnode * IN_DIM + k0 + lk];
      xa0 = *(const float4*)(xp);
      xa1 = *(const float4*)(xp + 4);
      xa2 = *(const float4*)(xp + 8);
      xa3 = *(const float4*)(xp + 12);
    } else {
      xa0 = xa1 = xa2 = xa3 = make_float4(0.f, 0.f, 0.f, 0.f);
    }
    const float* wbase = (w < 2) ? &Wl[(size_t)(k0 + wk) * HID + 32 * w]
                                 : &Wr[(size_t)(k0 + wk) * HID + 32 * w - 64];
    float4 wv[8];
#pragma unroll
    for (int q = 0; q < 8; ++q) wv[q] = *(const float4*)(wbase + 4 * q);

    xs[lk + 0][xcol] = xa0.x;
    xs[lk + 1][xcol] = xa0.y;
    xs[lk + 2][xcol] = xa0.z;
    xs[lk + 3][xcol] = xa0.w;
    xs[lk + 4][xcol] = xa1.x;
    xs[lk + 5][xcol] = xa1.y;
    xs[lk + 6][xcol] = xa1.z;
    xs[lk + 7][xcol] = xa1.w;
    xs[lk + 8][xcol] = xa2.x;
    xs[lk + 9][xcol] = xa2.y;
    xs[lk + 10][xcol] = xa2.z;
    xs[lk + 11][xcol] = xa2.w;
    xs[lk + 12][xcol] = xa3.x;
    xs[lk + 13][xcol] = xa3.y;
    xs[lk + 14][xcol] = xa3.z;
    xs[lk + 15][xcol] = xa3.w;
    // chunk cc = 4w+q2 (cols 8cc..8cc+7): low 4 -> ws[wk][4cc], high -> +64
#pragma unroll
    for (int q2 = 0; q2 < 4; ++q2) {
      const int cc = 4 * w + q2;
      *(float4*)&ws[wk][4 * cc] = wv[2 * q2];
      *(float4*)&ws[wk][64 + 4 * cc] = wv[2 * q2 + 1];
    }
    __syncthreads();
#pragma unroll
    for (int k = 0; k < BK; ++k) {
      const int aoff = (k < 16) ? 0 : 4;
      float a[8], b[8];
      *(float4*)&a[0] = *(const float4*)&xs[k][r * 8 + aoff];
      *(float4*)&a[4] = *(const float4*)&xs[k][r * 8 + 4 + aoff];
      *(float4*)&b[0] = *(const float4*)&ws[k][c * 4];
      *(float4*)&b[4] = *(const float4*)&ws[k][64 + c * 4];
#pragma unroll
      for (int i = 0; i < 8; ++i)
#pragma unroll
        for (int j = 0; j < 8; ++j) acc[i][j] += a[i] * b[j];
    }
    __syncthreads();
  }
#pragma unroll
  for (int i = 0; i < 8; ++i) {
    const int n = n0 + r * 8 + i;
    if (n < N) {
      float* dst = (c < 8) ? &xW[(size_t)n * HID + c * 8]
                           : &xWr[(size_t)n * HID + (c - 8) * 8];
      *(float4*)&dst[0] = *(float4*)&acc[i][0];
      *(float4*)&dst[4] = *(float4*)&acc[i][4];
    }
  }
}

// ---- CSR build ------------------------------------------------------------
__global__ __launch_bounds__(256) void count_kernel(const int* __restrict__ ei,
                                                    int* __restrict__ deg_i,
                                                    int E) {
  const int e = blockIdx.x * blockDim.x + threadIdx.x;
  if (e < E) atomicAdd(&deg_i[ei[E + e]], 1);
}

__global__ __launch_bounds__(SCAN_B) void scan1_kernel(
    const int* __restrict__ in, int* __restrict__ incl, int* __restrict__ bsum,
    int n) {
  __shared__ int s[SCAN_B];
  const int t = threadIdx.x;
  const int i = blockIdx.x * SCAN_B + t;
  int v = (i < n) ? in[i] : 0;
  s[t] = v;
  for (int off = 1; off < SCAN_B; off <<= 1) {
    __syncthreads();
    const int a = (t >= off) ? s[t - off] : 0;
    __syncthreads();
    s[t] += a;
  }
  if (i < n) incl[i] = s[t];
  if (t == SCAN_B - 1) bsum[blockIdx.x] = s[t];
}

__global__ __launch_bounds__(SCAN_B) void scan2_kernel(
    const int* __restrict__ bsum, int* __restrict__ boff, int nb) {
  __shared__ int s[SCAN_B];
  const int t = threadIdx.x;
  const int v = (t < nb) ? bsum[t] : 0;
  s[t] = v;
  for (int off = 1; off < SCAN_B; off <<= 1) {
    __syncthreads();
    const int a = (t >= off) ? s[t - off] : 0;
    __syncthreads();
    s[t] += a;
  }
  if (t < nb) boff[t] = s[t] - v;  // exclusive
}

__global__ __launch_bounds__(256) void scan3_kernel(
    const int* __restrict__ incl, const int* __restrict__ deg_i,
    const int* __restrict__ boff, int* __restrict__ row_off,
    int* __restrict__ cursor, int n) {
  const int i = blockIdx.x * blockDim.x + threadIdx.x;
  if (i < n) {
    const int st = incl[i] - deg_i[i] + boff[i >> 10];
    row_off[i] = st;
    cursor[i] = st;
  }
}

__global__ __launch_bounds__(256) void fill_kernel(const int* __restrict__ ei,
                                                   int* __restrict__ cursor,
                                                   int* __restrict__ csr_src,
                                                   int E) {
  const int e = blockIdx.x * blockDim.x + threadIdx.x;
  if (e < E) {
    const int s = ei[e];
    const int d = ei[E + e];
    const int pos = atomicAdd(&cursor[d], 1);
    csr_src[pos] = s;
  }
}

// ---- gather1: agg = sum_j xW[src]; h = relu(agg/deg + xWr + b1);
//      pl = h @ Wl2, pr = h @ Wr2  (all fused, wave per node) ---------------
__global__ __launch_bounds__(256) void gather1_kernel(
    const int* __restrict__ row_off, const int* __restrict__ deg_i,
    const int* __restrict__ csr_src, const float* __restrict__ xW,
    const float* __restrict__ xWr, const float* __restrict__ b1,
    const float* __restrict__ Wl2, const float* __restrict__ Wr2,
    float* __restrict__ pl, float* __restrict__ pr, int N) {
  const int lane = threadIdx.x & 63;
  const float wl0 = Wl2[lane * 3 + 0], wl1 = Wl2[lane * 3 + 1],
              wl2v = Wl2[lane * 3 + 2];
  const float wr0 = Wr2[lane * 3 + 0], wr1 = Wr2[lane * 3 + 1],
              wr2v = Wr2[lane * 3 + 2];
  const float bb = b1[lane];
  const int wave = (blockIdx.x * blockDim.x + threadIdx.x) >> 6;
  const int nwaves = (gridDim.x * blockDim.x) >> 6;
  for (int n = wave; n < N; n += nwaves) {
    const int start = row_off[n];
    const int dg = deg_i[n];
    float a0 = 0.f, a1 = 0.f, a2 = 0.f, a3 = 0.f;
    int r = 0;
    for (; r + 3 < dg; r += 4) {
      const int s0 = csr_src[start + r];
      const int s1 = csr_src[start + r + 1];
      const int s2 = csr_src[start + r + 2];
      const int s3 = csr_src[start + r + 3];
      a0 += xW[(size_t)s0 * HID + lane];
      a1 += xW[(size_t)s1 * HID + lane];
      a2 += xW[(size_t)s2 * HID + lane];
      a3 += xW[(size_t)s3 * HID + lane];
    }
    for (; r < dg; ++r) a0 += xW[(size_t)csr_src[start + r] * HID + lane];
    const float dinv = 1.0f / fmaxf((float)dg, 1.0f);
    const float hv = fmaxf(
        ((a0 + a1) + (a2 + a3)) * dinv + xWr[(size_t)n * HID + lane] + bb,
        0.0f);
    float v0 = hv * wl0, v1 = hv * wl1, v2 = hv * wl2v;
    float v3 = hv * wr0, v4 = hv * wr1, v5 = hv * wr2v;
#pragma unroll
    for (int off = 32; off >= 1; off >>= 1) {
      v0 += __shfl_down(v0, off);
      v1 += __shfl_down(v1, off);
      v2 += __shfl_down(v2, off);
      v3 += __shfl_down(v3, off);
      v4 += __shfl_down(v4, off);
      v5 += __shfl_down(v5, off);
    }
    if (lane == 0) {
      pl[(size_t)n * 3 + 0] = v0;
      pl[(size_t)n * 3 + 1] = v1;
      pl[(size_t)n * 3 + 2] = v2;
      pr[(size_t)n * 3 + 0] = v3;
      pr[(size_t)n * 3 + 1] = v4;
      pr[(size_t)n * 3 + 2] = v5;
    }
  }
}

// ---- final: gather pl over neighbors, log_softmax -------------------------
__global__ __launch_bounds__(256) void final_kernel(
    const int* __restrict__ row_off, const int* __restrict__ deg_i,
    const int* __restrict__ csr_src, const float* __restrict__ pl,
    const float* __restrict__ pr, const float* __restrict__ b2,
    float* __restrict__ out, int N) {
  const int stride = gridDim.x * blockDim.x;
  const float b20 = b2[0], b21 = b2[1], b22 = b2[2];
  for (int n = blockIdx.x * blockDim.x + threadIdx.x; n < N; n += stride) {
    const int start = row_off[n];
    const int dg = deg_i[n];
    float s0 = 0.f, s1 = 0.f, s2 = 0.f;
    for (int r = 0; r < dg; ++r) {
      const int s = csr_src[start + r];
      s0 += pl[(size_t)s * 3 + 0];
      s1 += pl[(size_t)s * 3 + 1];
      s2 += pl[(size_t)s * 3 + 2];
    }
    const float dinv = 1.0f / fmaxf((float)dg, 1.0f);
    const float v0 = s0 * dinv + pr[(size_t)n * 3 + 0] + b20;
    const float v1 = s1 * dinv + pr[(size_t)n * 3 + 1] + b21;
    const float v2 = s2 * dinv + pr[(size_t)n * 3 + 2] + b22;
    const float m = fmaxf(fmaxf(v0, v1), v2);
    const float e0 = __expf(v0 - m), e1 = __expf(v1 - m), e2 = __expf(v2 - m);
    const float lse = __logf(e0 + e1 + e2);
    out[(size_t)n * 3 + 0] = v0 - m - lse;
    out[(size_t)n * 3 + 1] = v1 - m - lse;
    out[(size_t)n * 3 + 2] = v2 - m - lse;
  }
}

extern "C" void kernel_launch(void* const* d_in, const int* in_sizes, int n_in,
                              void* d_out, int out_size, void* d_ws,
                              size_t ws_size, hipStream_t stream) {
  const float* x = (const float*)d_in[0];
  const int* ei = (const int*)d_in[1];  // int32 (JAX x64 disabled)
  const float* Wl1 = (const float*)d_in[2];
  const float* Wr1 = (const float*)d_in[3];
  const float* b1 = (const float*)d_in[4];
  const float* Wl2 = (const float*)d_in[5];
  const float* Wr2 = (const float*)d_in[6];
  const float* b2 = (const float*)d_in[7];
  float* out = (float*)d_out;

  const int N = in_sizes[0] / IN_DIM;
  const int E = in_sizes[1] / 2;
  const int nb1 = (N + SCAN_B - 1) / SCAN_B;

  int* wsI = (int*)d_ws;
  int* deg_i = wsI;              // [N]
  int* row_off = deg_i + N;      // [N]
  int* cursor = row_off + N;     // [N]
  int* incl = cursor + N;        // [N]
  int* bsum = incl + N;          // [SCAN_B]
  int* boff = bsum + SCAN_B;     // [SCAN_B]
  int* csr_src = boff + SCAN_B;  // [E]
  float* xW = (float*)(csr_src + E);  // [N*64]
  float* xWr = xW + (size_t)N * HID;  // [N*64]
  float* pl = xWr + (size_t)N * HID;  // [N*3]
  float* pr = pl + (size_t)N * 3;     // [N*3]

  hipMemsetAsync(deg_i, 0, (size_t)N * sizeof(int), stream);

  proj1_kernel<<<(N + BM - 1) / BM, 128, 0, stream>>>(x, Wl1, Wr1, xW, xWr, N);
  count_kernel<<<(E + 255) / 256, 256, 0, stream>>>(ei, deg_i, E);
  scan1_kernel<<<nb1, SCAN_B, 0, stream>>>(deg_i, incl, bsum, N);
  scan2_kernel<<<1, SCAN_B, 0, stream>>>(bsum, boff, nb1);
  scan3_kernel<<<(N + 255) / 256, 256, 0, stream>>>(incl, deg_i, boff, row_off,
                                                    cursor, N);
  fill_kernel<<<(E + 255) / 256, 256, 0, stream>>>(ei, cursor, csr_src, E);
  gather1_kernel<<<2048, 256, 0, stream>>>(row_off, deg_i, csr_src, xW, xWr,
                                           b1, Wl2, Wr2, pl, pr, N);
  final_kernel<<<(N + 255) / 256, 256, 0, stream>>>(row_off, deg_i, csr_src,
                                                    pl, pr, b2, out, N);
}

// Round 8
// 165.067 us; speedup vs baseline: 1.3076x; 1.2301x over previous
//
#include <hip/hip_runtime.h>
#include <hip/hip_bf16.h>

#define IN_DIM 128
#define HID 64
#define BM 64
#define SCAN_B 1024
#define WSTR 136  // f16 LDS row stride (pad: 2-way bank access, free)

using half8 = __attribute__((ext_vector_type(8))) _Float16;
using f32x4 = __attribute__((ext_vector_type(4))) float;

// ---- proj1: [xW | xWr] = x @ [Wl1 | Wr1]  via f16 MFMA, fp32 accumulate ---
// Block: 256 thr (4 waves), 64 nodes. Wave w: nodes w*16..w*16+15, all 128
// cols. A/B frags use the same (g,j)->k bijection k = kt*32 + g*8 + j, so the
// contraction is layout-safe; C/D mapping is the m89-verified one.
__global__ __launch_bounds__(256) void proj1_kernel(
    const float* __restrict__ x, const float* __restrict__ Wl,
    const float* __restrict__ Wr, float* __restrict__ xW,
    float* __restrict__ xWr, int N) {
  __shared__ _Float16 wsT[128][WSTR];  // [col][k]   34816 B
  __shared__ _Float16 xsT[64][WSTR];   // [node][k]  17408 B
  const int tx = threadIdx.x;
  const int n0 = blockIdx.x * BM;

  // ---- stage W^T (once per block): 16384 elems, 64 per thread ----
#pragma unroll 8
  for (int it = 0; it < 64; ++it) {
    const int flat = it * 256 + tx;
    const int k = flat >> 7;
    const int col = flat & 127;
    const float v = (col < 64) ? Wl[k * HID + col] : Wr[k * HID + col - 64];
    wsT[col][k] = (_Float16)v;
  }

  // ---- stage x tile: node = tx>>2, k-quarter q = tx&3 (32 k each) ----
  {
    const int node = tx >> 2;
    const int q = tx & 3;
    const int gn = n0 + node;
    if (gn < N) {
      const float4* xp = (const float4*)&x[(size_t)gn * IN_DIM + q * 32];
#pragma unroll
      for (int j = 0; j < 4; ++j) {
        const float4 u = xp[2 * j];
        const float4 v = xp[2 * j + 1];
        half8 h;
        h[0] = (_Float16)u.x; h[1] = (_Float16)u.y;
        h[2] = (_Float16)u.z; h[3] = (_Float16)u.w;
        h[4] = (_Float16)v.x; h[5] = (_Float16)v.y;
        h[6] = (_Float16)v.z; h[7] = (_Float16)v.w;
        *(half8*)&xsT[node][q * 32 + j * 8] = h;
      }
    } else {
      const half8 hz = {0, 0, 0, 0, 0, 0, 0, 0};
#pragma unroll
      for (int j = 0; j < 4; ++j) *(half8*)&xsT[node][q * 32 + j * 8] = hz;
    }
  }
  __syncthreads();

  // ---- MFMA: wave wv, lane l. a: node row = l&15, k = kt*32+(l>>4)*8+j ----
  const int lane = tx & 63;
  const int wv = tx >> 6;
  const int lrow = lane & 15;
  const int g = lane >> 4;

  f32x4 acc[8];
#pragma unroll
  for (int ct = 0; ct < 8; ++ct) acc[ct] = (f32x4){0.f, 0.f, 0.f, 0.f};

#pragma unroll
  for (int kt = 0; kt < 4; ++kt) {
    const half8 a = *(const half8*)&xsT[wv * 16 + lrow][kt * 32 + g * 8];
#pragma unroll
    for (int ct = 0; ct < 8; ++ct) {
      const half8 b = *(const half8*)&wsT[ct * 16 + lrow][kt * 32 + g * 8];
      acc[ct] = __builtin_amdgcn_mfma_f32_16x16x32_f16(a, b, acc[ct], 0, 0, 0);
    }
  }

  // ---- C write: col = ct*16 + (l&15), row(node) = wv*16 + g*4 + reg ----
#pragma unroll
  for (int ct = 0; ct < 8; ++ct) {
    const int col = ct * 16 + lrow;
#pragma unroll
    for (int reg = 0; reg < 4; ++reg) {
      const int node = n0 + wv * 16 + g * 4 + reg;
      if (node < N) {
        if (col < 64)
          xW[(size_t)node * HID + col] = acc[ct][reg];
        else
          xWr[(size_t)node * HID + col - 64] = acc[ct][reg];
      }
    }
  }
}

// ---- CSR build ------------------------------------------------------------
__global__ __launch_bounds__(256) void count_kernel(const int* __restrict__ ei,
                                                    int* __restrict__ deg_i,
                                                    int E) {
  const int e = blockIdx.x * blockDim.x + threadIdx.x;
  if (e < E) atomicAdd(&deg_i[ei[E + e]], 1);
}

__global__ __launch_bounds__(SCAN_B) void scan1_kernel(
    const int* __restrict__ in, int* __restrict__ incl, int* __restrict__ bsum,
    int n) {
  __shared__ int s[SCAN_B];
  const int t = threadIdx.x;
  const int i = blockIdx.x * SCAN_B + t;
  int v = (i < n) ? in[i] : 0;
  s[t] = v;
  for (int off = 1; off < SCAN_B; off <<= 1) {
    __syncthreads();
    const int a = (t >= off) ? s[t - off] : 0;
    __syncthreads();
    s[t] += a;
  }
  if (i < n) incl[i] = s[t];
  if (t == SCAN_B - 1) bsum[blockIdx.x] = s[t];
}

__global__ __launch_bounds__(SCAN_B) void scan2_kernel(
    const int* __restrict__ bsum, int* __restrict__ boff, int nb) {
  __shared__ int s[SCAN_B];
  const int t = threadIdx.x;
  const int v = (t < nb) ? bsum[t] : 0;
  s[t] = v;
  for (int off = 1; off < SCAN_B; off <<= 1) {
    __syncthreads();
    const int a = (t >= off) ? s[t - off] : 0;
    __syncthreads();
    s[t] += a;
  }
  if (t < nb) boff[t] = s[t] - v;  // exclusive
}

__global__ __launch_bounds__(256) void scan3_kernel(
    const int* __restrict__ incl, const int* __restrict__ deg_i,
    const int* __restrict__ boff, int* __restrict__ row_off,
    int* __restrict__ cursor, int n) {
  const int i = blockIdx.x * blockDim.x + threadIdx.x;
  if (i < n) {
    const int st = incl[i] - deg_i[i] + boff[i >> 10];
    row_off[i] = st;
    cursor[i] = st;
  }
}

__global__ __launch_bounds__(256) void fill_kernel(const int* __restrict__ ei,
                                                   int* __restrict__ cursor,
                                                   int* __restrict__ csr_src,
                                                   int E) {
  const int e = blockIdx.x * blockDim.x + threadIdx.x;
  if (e < E) {
    const int s = ei[e];
    const int d = ei[E + e];
    const int pos = atomicAdd(&cursor[d], 1);
    csr_src[pos] = s;
  }
}

// ---- gather1: agg = sum_j xW[src]; h = relu(agg/deg + xWr + b1);
//      pl = h @ Wl2, pr = h @ Wr2  (all fused, wave per node) ---------------
__global__ __launch_bounds__(256) void gather1_kernel(
    const int* __restrict__ row_off, const int* __restrict__ deg_i,
    const int* __restrict__ csr_src, const float* __restrict__ xW,
    const float* __restrict__ xWr, const float* __restrict__ b1,
    const float* __restrict__ Wl2, const float* __restrict__ Wr2,
    float* __restrict__ pl, float* __restrict__ pr, int N) {
  const int lane = threadIdx.x & 63;
  const float wl0 = Wl2[lane * 3 + 0], wl1 = Wl2[lane * 3 + 1],
              wl2v = Wl2[lane * 3 + 2];
  const float wr0 = Wr2[lane * 3 + 0], wr1 = Wr2[lane * 3 + 1],
              wr2v = Wr2[lane * 3 + 2];
  const float bb = b1[lane];
  const int wave = (blockIdx.x * blockDim.x + threadIdx.x) >> 6;
  const int nwaves = (gridDim.x * blockDim.x) >> 6;
  for (int n = wave; n < N; n += nwaves) {
    const int start = row_off[n];
    const int dg = deg_i[n];
    float a0 = 0.f, a1 = 0.f, a2 = 0.f, a3 = 0.f;
    int r = 0;
    for (; r + 3 < dg; r += 4) {
      const int s0 = csr_src[start + r];
      const int s1 = csr_src[start + r + 1];
      const int s2 = csr_src[start + r + 2];
      const int s3 = csr_src[start + r + 3];
      a0 += xW[(size_t)s0 * HID + lane];
      a1 += xW[(size_t)s1 * HID + lane];
      a2 += xW[(size_t)s2 * HID + lane];
      a3 += xW[(size_t)s3 * HID + lane];
    }
    for (; r < dg; ++r) a0 += xW[(size_t)csr_src[start + r] * HID + lane];
    const float dinv = 1.0f / fmaxf((float)dg, 1.0f);
    const float hv = fmaxf(
        ((a0 + a1) + (a2 + a3)) * dinv + xWr[(size_t)n * HID + lane] + bb,
        0.0f);
    float v0 = hv * wl0, v1 = hv * wl1, v2 = hv * wl2v;
    float v3 = hv * wr0, v4 = hv * wr1, v5 = hv * wr2v;
#pragma unroll
    for (int off = 32; off >= 1; off >>= 1) {
      v0 += __shfl_down(v0, off);
      v1 += __shfl_down(v1, off);
      v2 += __shfl_down(v2, off);
      v3 += __shfl_down(v3, off);
      v4 += __shfl_down(v4, off);
      v5 += __shfl_down(v5, off);
    }
    if (lane == 0) {
      pl[(size_t)n * 3 + 0] = v0;
      pl[(size_t)n * 3 + 1] = v1;
      pl[(size_t)n * 3 + 2] = v2;
      pr[(size_t)n * 3 + 0] = v3;
      pr[(size_t)n * 3 + 1] = v4;
      pr[(size_t)n * 3 + 2] = v5;
    }
  }
}

// ---- final: gather pl over neighbors, log_softmax -------------------------
__global__ __launch_bounds__(256) void final_kernel(
    const int* __restrict__ row_off, const int* __restrict__ deg_i,
    const int* __restrict__ csr_src, const float* __restrict__ pl,
    const float* __restrict__ pr, const float* __restrict__ b2,
    float* __restrict__ out, int N) {
  const int stride = gridDim.x * blockDim.x;
  const float b20 = b2[0], b21 = b2[1], b22 = b2[2];
  for (int n = blockIdx.x * blockDim.x + threadIdx.x; n < N; n += stride) {
    const int start = row_off[n];
    const int dg = deg_i[n];
    float s0 = 0.f, s1 = 0.f, s2 = 0.f;
    for (int r = 0; r < dg; ++r) {
      const int s = csr_src[start + r];
      s0 += pl[(size_t)s * 3 + 0];
      s1 += pl[(size_t)s * 3 + 1];
      s2 += pl[(size_t)s * 3 + 2];
    }
    const float dinv = 1.0f / fmaxf((float)dg, 1.0f);
    const float v0 = s0 * dinv + pr[(size_t)n * 3 + 0] + b20;
    const float v1 = s1 * dinv + pr[(size_t)n * 3 + 1] + b21;
    const float v2 = s2 * dinv + pr[(size_t)n * 3 + 2] + b22;
    const float m = fmaxf(fmaxf(v0, v1), v2);
    const float e0 = __expf(v0 - m), e1 = __expf(v1 - m), e2 = __expf(v2 - m);
    const float lse = __logf(e0 + e1 + e2);
    out[(size_t)n * 3 + 0] = v0 - m - lse;
    out[(size_t)n * 3 + 1] = v1 - m - lse;
    out[(size_t)n * 3 + 2] = v2 - m - lse;
  }
}

extern "C" void kernel_launch(void* const* d_in, const int* in_sizes, int n_in,
                              void* d_out, int out_size, void* d_ws,
                              size_t ws_size, hipStream_t stream) {
  const float* x = (const float*)d_in[0];
  const int* ei = (const int*)d_in[1];  // int32 (JAX x64 disabled)
  const float* Wl1 = (const float*)d_in[2];
  const float* Wr1 = (const float*)d_in[3];
  const float* b1 = (const float*)d_in[4];
  const float* Wl2 = (const float*)d_in[5];
  const float* Wr2 = (const float*)d_in[6];
  const float* b2 = (const float*)d_in[7];
  float* out = (float*)d_out;

  const int N = in_sizes[0] / IN_DIM;
  const int E = in_sizes[1] / 2;
  const int nb1 = (N + SCAN_B - 1) / SCAN_B;

  int* wsI = (int*)d_ws;
  int* deg_i = wsI;              // [N]
  int* row_off = deg_i + N;      // [N]
  int* cursor = row_off + N;     // [N]
  int* incl = cursor + N;        // [N]
  int* bsum = incl + N;          // [SCAN_B]
  int* boff = bsum + SCAN_B;     // [SCAN_B]
  int* csr_src = boff + SCAN_B;  // [E]
  float* xW = (float*)(csr_src + E);  // [N*64]
  float* xWr = xW + (size_t)N * HID;  // [N*64]
  float* pl = xWr + (size_t)N * HID;  // [N*3]
  float* pr = pl + (size_t)N * 3;     // [N*3]

  hipMemsetAsync(deg_i, 0, (size_t)N * sizeof(int), stream);

  proj1_kernel<<<(N + BM - 1) / BM, 256, 0, stream>>>(x, Wl1, Wr1, xW, xWr, N);
  count_kernel<<<(E + 255) / 256, 256, 0, stream>>>(ei, deg_i, E);
  scan1_kernel<<<nb1, SCAN_B, 0, stream>>>(deg_i, incl, bsum, N);
  scan2_kernel<<<1, SCAN_B, 0, stream>>>(bsum, boff, nb1);
  scan3_kernel<<<(N + 255) / 256, 256, 0, stream>>>(incl, deg_i, boff, row_off,
                                                    cursor, N);
  fill_kernel<<<(E + 255) / 256, 256, 0, stream>>>(ei, cursor, csr_src, E);
  gather1_kernel<<<2048, 256, 0, stream>>>(row_off, deg_i, csr_src, xW, xWr,
                                           b1, Wl2, Wr2, pl, pr, N);
  final_kernel<<<(N + 255) / 256, 256, 0, stream>>>(row_off, deg_i, csr_src,
                                                    pl, pr, b2, out, N);
}

// Round 9
// 158.421 us; speedup vs baseline: 1.3624x; 1.0419x over previous
//
#include <hip/hip_runtime.h>
#include <hip/hip_bf16.h>

#define IN_DIM 128
#define HID 64
#define BM 64
#define SCAN_B 1024
#define WSTR 136  // f16 LDS row stride (pad: 2-way bank access, free)

using half8 = __attribute__((ext_vector_type(8))) _Float16;
using f32x4 = __attribute__((ext_vector_type(4))) float;

// ---- proj1: [xW | xWr] = x @ [Wl1 | Wr1]  via f16 MFMA, fp32 accumulate ---
// Outputs stored as f16 (halves gather traffic in the next stage).
__global__ __launch_bounds__(256) void proj1_kernel(
    const float* __restrict__ x, const float* __restrict__ Wl,
    const float* __restrict__ Wr, _Float16* __restrict__ xW,
    _Float16* __restrict__ xWr, int N) {
  __shared__ _Float16 wsT[128][WSTR];  // [col][k]   34816 B
  __shared__ _Float16 xsT[64][WSTR];   // [node][k]  17408 B
  const int tx = threadIdx.x;
  const int n0 = blockIdx.x * BM;

  // ---- stage W^T (once per block): 16384 elems, 64 per thread ----
#pragma unroll 8
  for (int it = 0; it < 64; ++it) {
    const int flat = it * 256 + tx;
    const int k = flat >> 7;
    const int col = flat & 127;
    const float v = (col < 64) ? Wl[k * HID + col] : Wr[k * HID + col - 64];
    wsT[col][k] = (_Float16)v;
  }

  // ---- stage x tile: node = tx>>2, k-quarter q = tx&3 (32 k each) ----
  {
    const int node = tx >> 2;
    const int q = tx & 3;
    const int gn = n0 + node;
    if (gn < N) {
      const float4* xp = (const float4*)&x[(size_t)gn * IN_DIM + q * 32];
#pragma unroll
      for (int j = 0; j < 4; ++j) {
        const float4 u = xp[2 * j];
        const float4 v = xp[2 * j + 1];
        half8 h;
        h[0] = (_Float16)u.x; h[1] = (_Float16)u.y;
        h[2] = (_Float16)u.z; h[3] = (_Float16)u.w;
        h[4] = (_Float16)v.x; h[5] = (_Float16)v.y;
        h[6] = (_Float16)v.z; h[7] = (_Float16)v.w;
        *(half8*)&xsT[node][q * 32 + j * 8] = h;
      }
    } else {
      const half8 hz = {0, 0, 0, 0, 0, 0, 0, 0};
#pragma unroll
      for (int j = 0; j < 4; ++j) *(half8*)&xsT[node][q * 32 + j * 8] = hz;
    }
  }
  __syncthreads();

  // ---- MFMA: wave wv, lane l. a: node row = l&15, k = kt*32+(l>>4)*8+j ----
  const int lane = tx & 63;
  const int wv = tx >> 6;
  const int lrow = lane & 15;
  const int g = lane >> 4;

  f32x4 acc[8];
#pragma unroll
  for (int ct = 0; ct < 8; ++ct) acc[ct] = (f32x4){0.f, 0.f, 0.f, 0.f};

#pragma unroll
  for (int kt = 0; kt < 4; ++kt) {
    const half8 a = *(const half8*)&xsT[wv * 16 + lrow][kt * 32 + g * 8];
#pragma unroll
    for (int ct = 0; ct < 8; ++ct) {
      const half8 b = *(const half8*)&wsT[ct * 16 + lrow][kt * 32 + g * 8];
      acc[ct] = __builtin_amdgcn_mfma_f32_16x16x32_f16(a, b, acc[ct], 0, 0, 0);
    }
  }

  // ---- C write: col = ct*16 + (l&15), row(node) = wv*16 + g*4 + reg ----
#pragma unroll
  for (int ct = 0; ct < 8; ++ct) {
    const int col = ct * 16 + lrow;
#pragma unroll
    for (int reg = 0; reg < 4; ++reg) {
      const int node = n0 + wv * 16 + g * 4 + reg;
      if (node < N) {
        if (col < 64)
          xW[(size_t)node * HID + col] = (_Float16)acc[ct][reg];
        else
          xWr[(size_t)node * HID + col - 64] = (_Float16)acc[ct][reg];
      }
    }
  }
}

// ---- CSR build ------------------------------------------------------------
__global__ __launch_bounds__(256) void count_kernel(const int* __restrict__ ei,
                                                    int* __restrict__ deg_i,
                                                    int E) {
  const int e = blockIdx.x * blockDim.x + threadIdx.x;
  if (e < E) atomicAdd(&deg_i[ei[E + e]], 1);
}

__global__ __launch_bounds__(SCAN_B) void scan1_kernel(
    const int* __restrict__ in, int* __restrict__ incl, int* __restrict__ bsum,
    int n) {
  __shared__ int s[SCAN_B];
  const int t = threadIdx.x;
  const int i = blockIdx.x * SCAN_B + t;
  int v = (i < n) ? in[i] : 0;
  s[t] = v;
  for (int off = 1; off < SCAN_B; off <<= 1) {
    __syncthreads();
    const int a = (t >= off) ? s[t - off] : 0;
    __syncthreads();
    s[t] += a;
  }
  if (i < n) incl[i] = s[t];
  if (t == SCAN_B - 1) bsum[blockIdx.x] = s[t];
}

__global__ __launch_bounds__(SCAN_B) void scan2_kernel(
    const int* __restrict__ bsum, int* __restrict__ boff, int nb) {
  __shared__ int s[SCAN_B];
  const int t = threadIdx.x;
  const int v = (t < nb) ? bsum[t] : 0;
  s[t] = v;
  for (int off = 1; off < SCAN_B; off <<= 1) {
    __syncthreads();
    const int a = (t >= off) ? s[t - off] : 0;
    __syncthreads();
    s[t] += a;
  }
  if (t < nb) boff[t] = s[t] - v;  // exclusive
}

__global__ __launch_bounds__(256) void scan3_kernel(
    const int* __restrict__ incl, const int* __restrict__ deg_i,
    const int* __restrict__ boff, int* __restrict__ row_off,
    int* __restrict__ cursor, int n) {
  const int i = blockIdx.x * blockDim.x + threadIdx.x;
  if (i < n) {
    const int st = incl[i] - deg_i[i] + boff[i >> 10];
    row_off[i] = st;
    cursor[i] = st;
  }
}

__global__ __launch_bounds__(256) void fill_kernel(const int* __restrict__ ei,
                                                   int* __restrict__ cursor,
                                                   int* __restrict__ csr_src,
                                                   int E) {
  const int e = blockIdx.x * blockDim.x + threadIdx.x;
  if (e < E) {
    const int s = ei[e];
    const int d = ei[E + e];
    const int pos = atomicAdd(&cursor[d], 1);
    csr_src[pos] = s;
  }
}

// ---- gather1: agg = sum_j xW[src] (f16 rows); h = relu(agg/deg + xWr + b1);
//      pl = h @ Wl2, pr = h @ Wr2  (all fused, wave per node) ---------------
__global__ __launch_bounds__(256) void gather1_kernel(
    const int* __restrict__ row_off, const int* __restrict__ deg_i,
    const int* __restrict__ csr_src, const _Float16* __restrict__ xW,
    const _Float16* __restrict__ xWr, const float* __restrict__ b1,
    const float* __restrict__ Wl2, const float* __restrict__ Wr2,
    float* __restrict__ pl, float* __restrict__ pr, int N) {
  const int lane = threadIdx.x & 63;
  const float wl0 = Wl2[lane * 3 + 0], wl1 = Wl2[lane * 3 + 1],
              wl2v = Wl2[lane * 3 + 2];
  const float wr0 = Wr2[lane * 3 + 0], wr1 = Wr2[lane * 3 + 1],
              wr2v = Wr2[lane * 3 + 2];
  const float bb = b1[lane];
  const int wave = (blockIdx.x * blockDim.x + threadIdx.x) >> 6;
  const int nwaves = (gridDim.x * blockDim.x) >> 6;
  for (int n = wave; n < N; n += nwaves) {
    const int start = row_off[n];
    const int dg = deg_i[n];
    float a0 = 0.f, a1 = 0.f, a2 = 0.f, a3 = 0.f;
    int r = 0;
    for (; r + 3 < dg; r += 4) {
      const int s0 = csr_src[start + r];
      const int s1 = csr_src[start + r + 1];
      const int s2 = csr_src[start + r + 2];
      const int s3 = csr_src[start + r + 3];
      a0 += (float)xW[(size_t)s0 * HID + lane];
      a1 += (float)xW[(size_t)s1 * HID + lane];
      a2 += (float)xW[(size_t)s2 * HID + lane];
      a3 += (float)xW[(size_t)s3 * HID + lane];
    }
    for (; r < dg; ++r)
      a0 += (float)xW[(size_t)csr_src[start + r] * HID + lane];
    const float dinv = 1.0f / fmaxf((float)dg, 1.0f);
    const float hv =
        fmaxf(((a0 + a1) + (a2 + a3)) * dinv +
                  (float)xWr[(size_t)n * HID + lane] + bb,
              0.0f);
    float v0 = hv * wl0, v1 = hv * wl1, v2 = hv * wl2v;
    float v3 = hv * wr0, v4 = hv * wr1, v5 = hv * wr2v;
#pragma unroll
    for (int off = 32; off >= 1; off >>= 1) {
      v0 += __shfl_down(v0, off);
      v1 += __shfl_down(v1, off);
      v2 += __shfl_down(v2, off);
      v3 += __shfl_down(v3, off);
      v4 += __shfl_down(v4, off);
      v5 += __shfl_down(v5, off);
    }
    if (lane == 0) {
      pl[(size_t)n * 3 + 0] = v0;
      pl[(size_t)n * 3 + 1] = v1;
      pl[(size_t)n * 3 + 2] = v2;
      pr[(size_t)n * 3 + 0] = v3;
      pr[(size_t)n * 3 + 1] = v4;
      pr[(size_t)n * 3 + 2] = v5;
    }
  }
}

// ---- final: gather pl over neighbors, log_softmax -------------------------
__global__ __launch_bounds__(256) void final_kernel(
    const int* __restrict__ row_off, const int* __restrict__ deg_i,
    const int* __restrict__ csr_src, const float* __restrict__ pl,
    const float* __restrict__ pr, const float* __restrict__ b2,
    float* __restrict__ out, int N) {
  const int stride = gridDim.x * blockDim.x;
  const float b20 = b2[0], b21 = b2[1], b22 = b2[2];
  for (int n = blockIdx.x * blockDim.x + threadIdx.x; n < N; n += stride) {
    const int start = row_off[n];
    const int dg = deg_i[n];
    float s0 = 0.f, s1 = 0.f, s2 = 0.f;
    for (int r = 0; r < dg; ++r) {
      const int s = csr_src[start + r];
      s0 += pl[(size_t)s * 3 + 0];
      s1 += pl[(size_t)s * 3 + 1];
      s2 += pl[(size_t)s * 3 + 2];
    }
    const float dinv = 1.0f / fmaxf((float)dg, 1.0f);
    const float v0 = s0 * dinv + pr[(size_t)n * 3 + 0] + b20;
    const float v1 = s1 * dinv + pr[(size_t)n * 3 + 1] + b21;
    const float v2 = s2 * dinv + pr[(size_t)n * 3 + 2] + b22;
    const float m = fmaxf(fmaxf(v0, v1), v2);
    const float e0 = __expf(v0 - m), e1 = __expf(v1 - m), e2 = __expf(v2 - m);
    const float lse = __logf(e0 + e1 + e2);
    out[(size_t)n * 3 + 0] = v0 - m - lse;
    out[(size_t)n * 3 + 1] = v1 - m - lse;
    out[(size_t)n * 3 + 2] = v2 - m - lse;
  }
}

extern "C" void kernel_launch(void* const* d_in, const int* in_sizes, int n_in,
                              void* d_out, int out_size, void* d_ws,
                              size_t ws_size, hipStream_t stream) {
  const float* x = (const float*)d_in[0];
  const int* ei = (const int*)d_in[1];  // int32 (JAX x64 disabled)
  const float* Wl1 = (const float*)d_in[2];
  const float* Wr1 = (const float*)d_in[3];
  const float* b1 = (const float*)d_in[4];
  const float* Wl2 = (const float*)d_in[5];
  const float* Wr2 = (const float*)d_in[6];
  const float* b2 = (const float*)d_in[7];
  float* out = (float*)d_out;

  const int N = in_sizes[0] / IN_DIM;
  const int E = in_sizes[1] / 2;
  const int nb1 = (N + SCAN_B - 1) / SCAN_B;

  int* wsI = (int*)d_ws;
  int* deg_i = wsI;              // [N]
  int* row_off = deg_i + N;      // [N]
  int* cursor = row_off + N;     // [N]
  int* incl = cursor + N;        // [N]
  int* bsum = incl + N;          // [SCAN_B]
  int* boff = bsum + SCAN_B;     // [SCAN_B]
  int* csr_src = boff + SCAN_B;  // [E]
  _Float16* xW = (_Float16*)(csr_src + E);   // [N*64] f16
  _Float16* xWr = xW + (size_t)N * HID;      // [N*64] f16
  float* pl = (float*)(xWr + (size_t)N * HID);  // [N*3]
  float* pr = pl + (size_t)N * 3;               // [N*3]

  hipMemsetAsync(deg_i, 0, (size_t)N * sizeof(int), stream);

  proj1_kernel<<<(N + BM - 1) / BM, 256, 0, stream>>>(x, Wl1, Wr1, xW, xWr, N);
  count_kernel<<<(E + 255) / 256, 256, 0, stream>>>(ei, deg_i, E);
  scan1_kernel<<<nb1, SCAN_B, 0, stream>>>(deg_i, incl, bsum, N);
  scan2_kernel<<<1, SCAN_B, 0, stream>>>(bsum, boff, nb1);
  scan3_kernel<<<(N + 255) / 256, 256, 0, stream>>>(incl, deg_i, boff, row_off,
                                                    cursor, N);
  fill_kernel<<<(E + 255) / 256, 256, 0, stream>>>(ei, cursor, csr_src, E);
  gather1_kernel<<<2048, 256, 0, stream>>>(row_off, deg_i, csr_src, xW, xWr,
                                           b1, Wl2, Wr2, pl, pr, N);
  final_kernel<<<(N + 255) / 256, 256, 0, stream>>>(row_off, deg_i, csr_src,
                                                    pl, pr, b2, out, N);
}

// Round 10
// 151.286 us; speedup vs baseline: 1.4267x; 1.0472x over previous
//
#include <hip/hip_runtime.h>
#include <hip/hip_bf16.h>

#define IN_DIM 128
#define HID 64
#define BM 64
#define SCAN_B 1024
#define WSTR 136  // f16 LDS row stride (pad: 2-way bank access, free)

using half8 = __attribute__((ext_vector_type(8))) _Float16;
using f32x4 = __attribute__((ext_vector_type(4))) float;

// ---- wconv: pre-convert [Wl1|Wr1] to f16, transposed: wcatT[col][k] -------
__global__ __launch_bounds__(256) void wconv_kernel(
    const float* __restrict__ Wl, const float* __restrict__ Wr,
    _Float16* __restrict__ wcatT) {
  const int i = blockIdx.x * 256 + threadIdx.x;  // 64 blocks -> 16384 elems
  const int col = i >> 7;
  const int k = i & 127;
  const float v = (col < 64) ? Wl[k * HID + col] : Wr[k * HID + col - 64];
  wcatT[col * 128 + k] = (_Float16)v;
}

// ---- proj1: [xW | xWr] = x @ [Wl1 | Wr1]  via f16 MFMA, fp32 accumulate ---
__global__ __launch_bounds__(256) void proj1_kernel(
    const float* __restrict__ x, const _Float16* __restrict__ wcatT,
    _Float16* __restrict__ xW, _Float16* __restrict__ xWr, int N) {
  __shared__ _Float16 wsT[128][WSTR];  // [col][k]   34816 B
  __shared__ _Float16 xsT[64][WSTR];   // [node][k]  17408 B
  const int tx = threadIdx.x;
  const int n0 = blockIdx.x * BM;

  // ---- stage W^T: 2048 half8, 8 per thread (pre-converted f16) ----
#pragma unroll
  for (int it = 0; it < 8; ++it) {
    const int e8 = it * 256 + tx;
    const int col = e8 >> 4;
    const int k8 = (e8 & 15) * 8;
    *(half8*)&wsT[col][k8] = *(const half8*)&wcatT[col * 128 + k8];
  }

  // ---- stage x tile: node = tx>>2, k-quarter q = tx&3 (32 k each) ----
  {
    const int node = tx >> 2;
    const int q = tx & 3;
    const int gn = n0 + node;
    if (gn < N) {
      const float4* xp = (const float4*)&x[(size_t)gn * IN_DIM + q * 32];
#pragma unroll
      for (int j = 0; j < 4; ++j) {
        const float4 u = xp[2 * j];
        const float4 v = xp[2 * j + 1];
        half8 h;
        h[0] = (_Float16)u.x; h[1] = (_Float16)u.y;
        h[2] = (_Float16)u.z; h[3] = (_Float16)u.w;
        h[4] = (_Float16)v.x; h[5] = (_Float16)v.y;
        h[6] = (_Float16)v.z; h[7] = (_Float16)v.w;
        *(half8*)&xsT[node][q * 32 + j * 8] = h;
      }
    } else {
      const half8 hz = {0, 0, 0, 0, 0, 0, 0, 0};
#pragma unroll
      for (int j = 0; j < 4; ++j) *(half8*)&xsT[node][q * 32 + j * 8] = hz;
    }
  }
  __syncthreads();

  const int lane = tx & 63;
  const int wv = tx >> 6;
  const int lrow = lane & 15;
  const int g = lane >> 4;

  f32x4 acc[8];
#pragma unroll
  for (int ct = 0; ct < 8; ++ct) acc[ct] = (f32x4){0.f, 0.f, 0.f, 0.f};

#pragma unroll
  for (int kt = 0; kt < 4; ++kt) {
    const half8 a = *(const half8*)&xsT[wv * 16 + lrow][kt * 32 + g * 8];
#pragma unroll
    for (int ct = 0; ct < 8; ++ct) {
      const half8 b = *(const half8*)&wsT[ct * 16 + lrow][kt * 32 + g * 8];
      acc[ct] = __builtin_amdgcn_mfma_f32_16x16x32_f16(a, b, acc[ct], 0, 0, 0);
    }
  }

  // ---- C write: col = ct*16 + lrow, node = wv*16 + g*4 + reg ----
#pragma unroll
  for (int ct = 0; ct < 8; ++ct) {
    const int col = ct * 16 + lrow;
#pragma unroll
    for (int reg = 0; reg < 4; ++reg) {
      const int node = n0 + wv * 16 + g * 4 + reg;
      if (node < N) {
        if (col < 64)
          xW[(size_t)node * HID + col] = (_Float16)acc[ct][reg];
        else
          xWr[(size_t)node * HID + col - 64] = (_Float16)acc[ct][reg];
      }
    }
  }
}

// ---- CSR build ------------------------------------------------------------
__global__ __launch_bounds__(256) void count_kernel(const int* __restrict__ ei,
                                                    int* __restrict__ deg_i,
                                                    int E) {
  const int e = blockIdx.x * blockDim.x + threadIdx.x;
  if (e < E) atomicAdd(&deg_i[ei[E + e]], 1);
}

__global__ __launch_bounds__(SCAN_B) void scan1_kernel(
    const int* __restrict__ in, int* __restrict__ incl, int* __restrict__ bsum,
    int n) {
  __shared__ int s[SCAN_B];
  const int t = threadIdx.x;
  const int i = blockIdx.x * SCAN_B + t;
  int v = (i < n) ? in[i] : 0;
  s[t] = v;
  for (int off = 1; off < SCAN_B; off <<= 1) {
    __syncthreads();
    const int a = (t >= off) ? s[t - off] : 0;
    __syncthreads();
    s[t] += a;
  }
  if (i < n) incl[i] = s[t];
  if (t == SCAN_B - 1) bsum[blockIdx.x] = s[t];
}

__global__ __launch_bounds__(SCAN_B) void scan2_kernel(
    const int* __restrict__ bsum, int* __restrict__ boff, int nb) {
  __shared__ int s[SCAN_B];
  const int t = threadIdx.x;
  const int v = (t < nb) ? bsum[t] : 0;
  s[t] = v;
  for (int off = 1; off < SCAN_B; off <<= 1) {
    __syncthreads();
    const int a = (t >= off) ? s[t - off] : 0;
    __syncthreads();
    s[t] += a;
  }
  if (t < nb) boff[t] = s[t] - v;  // exclusive
}

__global__ __launch_bounds__(256) void scan3_kernel(
    const int* __restrict__ incl, const int* __restrict__ deg_i,
    const int* __restrict__ boff, int* __restrict__ row_off,
    int* __restrict__ cursor, int n) {
  const int i = blockIdx.x * blockDim.x + threadIdx.x;
  if (i < n) {
    const int st = incl[i] - deg_i[i] + boff[i >> 10];
    row_off[i] = st;
    cursor[i] = st;
  }
}

__global__ __launch_bounds__(256) void fill_kernel(const int* __restrict__ ei,
                                                   int* __restrict__ cursor,
                                                   int* __restrict__ csr_src,
                                                   int E) {
  const int e = blockIdx.x * blockDim.x + threadIdx.x;
  if (e < E) {
    const int s = ei[e];
    const int d = ei[E + e];
    const int pos = atomicAdd(&cursor[d], 1);
    csr_src[pos] = s;
  }
}

// ---- gather1: h[n] = relu(mean_j xW[src] + xWr[n] + b1), f16 out ----------
// Wave per node; NO cross-lane reduction (R9 lesson: shuffles dominated).
__global__ __launch_bounds__(256) void gather1_kernel(
    const int* __restrict__ row_off, const int* __restrict__ deg_i,
    const int* __restrict__ csr_src, const _Float16* __restrict__ xW,
    const _Float16* __restrict__ xWr, const float* __restrict__ b1,
    _Float16* __restrict__ h, int N) {
  const int lane = threadIdx.x & 63;
  const float bb = b1[lane];
  const int wave = (blockIdx.x * blockDim.x + threadIdx.x) >> 6;
  const int nwaves = (gridDim.x * blockDim.x) >> 6;
  for (int n = wave; n < N; n += nwaves) {
    const int start = row_off[n];
    const int dg = deg_i[n];
    float a0 = 0.f, a1 = 0.f, a2 = 0.f, a3 = 0.f;
    int r = 0;
    for (; r + 3 < dg; r += 4) {
      const int s0 = csr_src[start + r];
      const int s1 = csr_src[start + r + 1];
      const int s2 = csr_src[start + r + 2];
      const int s3 = csr_src[start + r + 3];
      a0 += (float)xW[(size_t)s0 * HID + lane];
      a1 += (float)xW[(size_t)s1 * HID + lane];
      a2 += (float)xW[(size_t)s2 * HID + lane];
      a3 += (float)xW[(size_t)s3 * HID + lane];
    }
    for (; r < dg; ++r)
      a0 += (float)xW[(size_t)csr_src[start + r] * HID + lane];
    const float dinv = 1.0f / fmaxf((float)dg, 1.0f);
    const float hv =
        fmaxf(((a0 + a1) + (a2 + a3)) * dinv +
                  (float)xWr[(size_t)n * HID + lane] + bb,
              0.0f);
    h[(size_t)n * HID + lane] = (_Float16)hv;
  }
}

// ---- proj2: [pl|pr] = h @ [Wl2|Wr2]  via MFMA (cols padded 6->16) ---------
__global__ __launch_bounds__(256) void proj2_kernel(
    const _Float16* __restrict__ h, const float* __restrict__ Wl2,
    const float* __restrict__ Wr2, float* __restrict__ pl,
    float* __restrict__ pr, int N) {
  __shared__ _Float16 wlds[16][72];  // [outc][k], outc>=6 zero
  const int tx = threadIdx.x;
  for (int i = tx; i < 1024; i += 256) {
    const int c = i >> 6;
    const int k = i & 63;
    float v = 0.f;
    if (c < 3) v = Wl2[k * 3 + c];
    else if (c < 6) v = Wr2[k * 3 + (c - 3)];
    wlds[c][k] = (_Float16)v;
  }
  __syncthreads();
  const int lane = tx & 63;
  const int wv = tx >> 6;
  const int lrow = lane & 15;
  const int g = lane >> 4;
  const int in_node = blockIdx.x * 64 + wv * 16 + lrow;

  f32x4 acc = (f32x4){0.f, 0.f, 0.f, 0.f};
#pragma unroll
  for (int kt = 0; kt < 2; ++kt) {
    half8 a;
    if (in_node < N)
      a = *(const half8*)&h[(size_t)in_node * HID + kt * 32 + g * 8];
    else
      a = (half8){0, 0, 0, 0, 0, 0, 0, 0};
    const half8 b = *(const half8*)&wlds[lrow][kt * 32 + g * 8];
    acc = __builtin_amdgcn_mfma_f32_16x16x32_f16(a, b, acc, 0, 0, 0);
  }
  // C: outc = lrow, node = blockBase + wv*16 + g*4 + reg
  const int outc = lrow;
  if (outc < 6) {
#pragma unroll
    for (int reg = 0; reg < 4; ++reg) {
      const int n = blockIdx.x * 64 + wv * 16 + g * 4 + reg;
      if (n < N) {
        if (outc < 3)
          pl[(size_t)n * 3 + outc] = acc[reg];
        else
          pr[(size_t)n * 3 + outc - 3] = acc[reg];
      }
    }
  }
}

// ---- final: gather pl over neighbors, log_softmax -------------------------
__global__ __launch_bounds__(256) void final_kernel(
    const int* __restrict__ row_off, const int* __restrict__ deg_i,
    const int* __restrict__ csr_src, const float* __restrict__ pl,
    const float* __restrict__ pr, const float* __restrict__ b2,
    float* __restrict__ out, int N) {
  const int stride = gridDim.x * blockDim.x;
  const float b20 = b2[0], b21 = b2[1], b22 = b2[2];
  for (int n = blockIdx.x * blockDim.x + threadIdx.x; n < N; n += stride) {
    const int start = row_off[n];
    const int dg = deg_i[n];
    float s0 = 0.f, s1 = 0.f, s2 = 0.f;
    for (int r = 0; r < dg; ++r) {
      const int s = csr_src[start + r];
      s0 += pl[(size_t)s * 3 + 0];
      s1 += pl[(size_t)s * 3 + 1];
      s2 += pl[(size_t)s * 3 + 2];
    }
    const float dinv = 1.0f / fmaxf((float)dg, 1.0f);
    const float v0 = s0 * dinv + pr[(size_t)n * 3 + 0] + b20;
    const float v1 = s1 * dinv + pr[(size_t)n * 3 + 1] + b21;
    const float v2 = s2 * dinv + pr[(size_t)n * 3 + 2] + b22;
    const float m = fmaxf(fmaxf(v0, v1), v2);
    const float e0 = __expf(v0 - m), e1 = __expf(v1 - m), e2 = __expf(v2 - m);
    const float lse = __logf(e0 + e1 + e2);
    out[(size_t)n * 3 + 0] = v0 - m - lse;
    out[(size_t)n * 3 + 1] = v1 - m - lse;
    out[(size_t)n * 3 + 2] = v2 - m - lse;
  }
}

extern "C" void kernel_launch(void* const* d_in, const int* in_sizes, int n_in,
                              void* d_out, int out_size, void* d_ws,
                              size_t ws_size, hipStream_t stream) {
  const float* x = (const float*)d_in[0];
  const int* ei = (const int*)d_in[1];  // int32 (JAX x64 disabled)
  const float* Wl1 = (const float*)d_in[2];
  const float* Wr1 = (const float*)d_in[3];
  const float* b1 = (const float*)d_in[4];
  const float* Wl2 = (const float*)d_in[5];
  const float* Wr2 = (const float*)d_in[6];
  const float* b2 = (const float*)d_in[7];
  float* out = (float*)d_out;

  const int N = in_sizes[0] / IN_DIM;
  const int E = in_sizes[1] / 2;
  const int nb1 = (N + SCAN_B - 1) / SCAN_B;

  int* wsI = (int*)d_ws;
  int* deg_i = wsI;              // [N]
  int* row_off = deg_i + N;      // [N]
  int* cursor = row_off + N;     // [N]
  int* incl = cursor + N;        // [N]
  int* bsum = incl + N;          // [SCAN_B]
  int* boff = bsum + SCAN_B;     // [SCAN_B]
  int* csr_src = boff + SCAN_B;  // [E]
  _Float16* wcatT = (_Float16*)(csr_src + E);   // [128*128] f16
  _Float16* xW = wcatT + 128 * 128;             // [N*64] f16
  _Float16* xWr = xW + (size_t)N * HID;         // [N*64] f16
  _Float16* h = xWr + (size_t)N * HID;          // [N*64] f16
  float* pl = (float*)(h + (size_t)N * HID);    // [N*3]
  float* pr = pl + (size_t)N * 3;               // [N*3]

  hipMemsetAsync(deg_i, 0, (size_t)N * sizeof(int), stream);

  wconv_kernel<<<64, 256, 0, stream>>>(Wl1, Wr1, wcatT);
  proj1_kernel<<<(N + BM - 1) / BM, 256, 0, stream>>>(x, wcatT, xW, xWr, N);
  count_kernel<<<(E + 255) / 256, 256, 0, stream>>>(ei, deg_i, E);
  scan1_kernel<<<nb1, SCAN_B, 0, stream>>>(deg_i, incl, bsum, N);
  scan2_kernel<<<1, SCAN_B, 0, stream>>>(bsum, boff, nb1);
  scan3_kernel<<<(N + 255) / 256, 256, 0, stream>>>(incl, deg_i, boff, row_off,
                                                    cursor, N);
  fill_kernel<<<(E + 255) / 256, 256, 0, stream>>>(ei, cursor, csr_src, E);
  gather1_kernel<<<2048, 256, 0, stream>>>(row_off, deg_i, csr_src, xW, xWr,
                                           b1, h, N);
  proj2_kernel<<<(N + 63) / 64, 256, 0, stream>>>(h, Wl2, Wr2, pl, pr, N);
  final_kernel<<<(N + 255) / 256, 256, 0, stream>>>(row_off, deg_i, csr_src,
                                                    pl, pr, b2, out, N);
}

// Round 11
// 141.014 us; speedup vs baseline: 1.5306x; 1.0728x over previous
//
#include <hip/hip_runtime.h>
#include <hip/hip_bf16.h>

#define IN_DIM 128
#define HID 64
#define BM 64
#define SCAN_B 1024
#define WSTR 136  // f16 LDS row stride (pad: 2-way bank access, free)

using half8 = __attribute__((ext_vector_type(8))) _Float16;
using f32x4 = __attribute__((ext_vector_type(4))) float;

// ---- wconv: pre-convert [Wl1|Wr1] to f16, transposed: wcatT[col][k] -------
__global__ __launch_bounds__(256) void wconv_kernel(
    const float* __restrict__ Wl, const float* __restrict__ Wr,
    _Float16* __restrict__ wcatT) {
  const int i = blockIdx.x * 256 + threadIdx.x;  // 64 blocks -> 16384 elems
  const int col = i >> 7;
  const int k = i & 127;
  const float v = (col < 64) ? Wl[k * HID + col] : Wr[k * HID + col - 64];
  wcatT[col * 128 + k] = (_Float16)v;
}

// ---- proj1: [xW | xWr] = x @ [Wl1 | Wr1]  via f16 MFMA, fp32 accumulate ---
__global__ __launch_bounds__(256) void proj1_kernel(
    const float* __restrict__ x, const _Float16* __restrict__ wcatT,
    _Float16* __restrict__ xW, _Float16* __restrict__ xWr, int N) {
  __shared__ _Float16 wsT[128][WSTR];  // [col][k]   34816 B
  __shared__ _Float16 xsT[64][WSTR];   // [node][k]  17408 B
  const int tx = threadIdx.x;
  const int n0 = blockIdx.x * BM;

  // ---- stage W^T: 2048 half8, 8 per thread (pre-converted f16) ----
#pragma unroll
  for (int it = 0; it < 8; ++it) {
    const int e8 = it * 256 + tx;
    const int col = e8 >> 4;
    const int k8 = (e8 & 15) * 8;
    *(half8*)&wsT[col][k8] = *(const half8*)&wcatT[col * 128 + k8];
  }

  // ---- stage x tile: node = tx>>2, k-quarter q = tx&3 (32 k each) ----
  {
    const int node = tx >> 2;
    const int q = tx & 3;
    const int gn = n0 + node;
    if (gn < N) {
      const float4* xp = (const float4*)&x[(size_t)gn * IN_DIM + q * 32];
#pragma unroll
      for (int j = 0; j < 4; ++j) {
        const float4 u = xp[2 * j];
        const float4 v = xp[2 * j + 1];
        half8 h;
        h[0] = (_Float16)u.x; h[1] = (_Float16)u.y;
        h[2] = (_Float16)u.z; h[3] = (_Float16)u.w;
        h[4] = (_Float16)v.x; h[5] = (_Float16)v.y;
        h[6] = (_Float16)v.z; h[7] = (_Float16)v.w;
        *(half8*)&xsT[node][q * 32 + j * 8] = h;
      }
    } else {
      const half8 hz = {0, 0, 0, 0, 0, 0, 0, 0};
#pragma unroll
      for (int j = 0; j < 4; ++j) *(half8*)&xsT[node][q * 32 + j * 8] = hz;
    }
  }
  __syncthreads();

  const int lane = tx & 63;
  const int wv = tx >> 6;
  const int lrow = lane & 15;
  const int g = lane >> 4;

  f32x4 acc[8];
#pragma unroll
  for (int ct = 0; ct < 8; ++ct) acc[ct] = (f32x4){0.f, 0.f, 0.f, 0.f};

#pragma unroll
  for (int kt = 0; kt < 4; ++kt) {
    const half8 a = *(const half8*)&xsT[wv * 16 + lrow][kt * 32 + g * 8];
#pragma unroll
    for (int ct = 0; ct < 8; ++ct) {
      const half8 b = *(const half8*)&wsT[ct * 16 + lrow][kt * 32 + g * 8];
      acc[ct] = __builtin_amdgcn_mfma_f32_16x16x32_f16(a, b, acc[ct], 0, 0, 0);
    }
  }

  // ---- C write: col = ct*16 + lrow, node = wv*16 + g*4 + reg ----
#pragma unroll
  for (int ct = 0; ct < 8; ++ct) {
    const int col = ct * 16 + lrow;
#pragma unroll
    for (int reg = 0; reg < 4; ++reg) {
      const int node = n0 + wv * 16 + g * 4 + reg;
      if (node < N) {
        if (col < 64)
          xW[(size_t)node * HID + col] = (_Float16)acc[ct][reg];
        else
          xWr[(size_t)node * HID + col - 64] = (_Float16)acc[ct][reg];
      }
    }
  }
}

// ---- CSR build ------------------------------------------------------------
// count: degree histogram AND per-edge rank (atomicAdd return), coalesced.
__global__ __launch_bounds__(256) void count_kernel(const int* __restrict__ ei,
                                                    int* __restrict__ deg_i,
                                                    int* __restrict__ eoff,
                                                    int E) {
  const int e = blockIdx.x * blockDim.x + threadIdx.x;
  if (e < E) eoff[e] = atomicAdd(&deg_i[ei[E + e]], 1);
}

__global__ __launch_bounds__(SCAN_B) void scan1_kernel(
    const int* __restrict__ in, int* __restrict__ incl, int* __restrict__ bsum,
    int n) {
  __shared__ int s[SCAN_B];
  const int t = threadIdx.x;
  const int i = blockIdx.x * SCAN_B + t;
  int v = (i < n) ? in[i] : 0;
  s[t] = v;
  for (int off = 1; off < SCAN_B; off <<= 1) {
    __syncthreads();
    const int a = (t >= off) ? s[t - off] : 0;
    __syncthreads();
    s[t] += a;
  }
  if (i < n) incl[i] = s[t];
  if (t == SCAN_B - 1) bsum[blockIdx.x] = s[t];
}

__global__ __launch_bounds__(SCAN_B) void scan2_kernel(
    const int* __restrict__ bsum, int* __restrict__ boff, int nb) {
  __shared__ int s[SCAN_B];
  const int t = threadIdx.x;
  const int v = (t < nb) ? bsum[t] : 0;
  s[t] = v;
  for (int off = 1; off < SCAN_B; off <<= 1) {
    __syncthreads();
    const int a = (t >= off) ? s[t - off] : 0;
    __syncthreads();
    s[t] += a;
  }
  if (t < nb) boff[t] = s[t] - v;  // exclusive
}

__global__ __launch_bounds__(256) void scan3_kernel(
    const int* __restrict__ incl, const int* __restrict__ deg_i,
    const int* __restrict__ boff, int* __restrict__ row_off, int n) {
  const int i = blockIdx.x * blockDim.x + threadIdx.x;
  if (i < n) row_off[i] = incl[i] - deg_i[i] + boff[i >> 10];
}

// fill: pos precomputed (row_off + eoff) -> no RMW chain; atomicExch store
// writes ~4B through to HBM (no per-XCD dirty-line amplification, R10 lesson).
__global__ __launch_bounds__(256) void fill_kernel(const int* __restrict__ ei,
                                                   const int* __restrict__ row_off,
                                                   const int* __restrict__ eoff,
                                                   int* __restrict__ csr_src,
                                                   int E) {
  const int e = blockIdx.x * blockDim.x + threadIdx.x;
  if (e < E) {
    const int s = ei[e];
    const int d = ei[E + e];
    atomicExch(&csr_src[row_off[d] + eoff[e]], s);
  }
}

// ---- gather1: h[n] = relu(mean_j xW[src] + xWr[n] + b1), f16 out ----------
__global__ __launch_bounds__(256) void gather1_kernel(
    const int* __restrict__ row_off, const int* __restrict__ deg_i,
    const int* __restrict__ csr_src, const _Float16* __restrict__ xW,
    const _Float16* __restrict__ xWr, const float* __restrict__ b1,
    _Float16* __restrict__ h, int N) {
  const int lane = threadIdx.x & 63;
  const float bb = b1[lane];
  const int wave = (blockIdx.x * blockDim.x + threadIdx.x) >> 6;
  const int nwaves = (gridDim.x * blockDim.x) >> 6;
  for (int n = wave; n < N; n += nwaves) {
    const int start = row_off[n];
    const int dg = deg_i[n];
    float a0 = 0.f, a1 = 0.f, a2 = 0.f, a3 = 0.f;
    int r = 0;
    for (; r + 3 < dg; r += 4) {
      const int s0 = csr_src[start + r];
      const int s1 = csr_src[start + r + 1];
      const int s2 = csr_src[start + r + 2];
      const int s3 = csr_src[start + r + 3];
      a0 += (float)xW[(size_t)s0 * HID + lane];
      a1 += (float)xW[(size_t)s1 * HID + lane];
      a2 += (float)xW[(size_t)s2 * HID + lane];
      a3 += (float)xW[(size_t)s3 * HID + lane];
    }
    for (; r < dg; ++r)
      a0 += (float)xW[(size_t)csr_src[start + r] * HID + lane];
    const float dinv = 1.0f / fmaxf((float)dg, 1.0f);
    const float hv =
        fmaxf(((a0 + a1) + (a2 + a3)) * dinv +
                  (float)xWr[(size_t)n * HID + lane] + bb,
              0.0f);
    h[(size_t)n * HID + lane] = (_Float16)hv;
  }
}

// ---- proj2: [pl|pr] = h @ [Wl2|Wr2]  via MFMA (cols padded 6->16) ---------
__global__ __launch_bounds__(256) void proj2_kernel(
    const _Float16* __restrict__ h, const float* __restrict__ Wl2,
    const float* __restrict__ Wr2, float* __restrict__ pl,
    float* __restrict__ pr, int N) {
  __shared__ _Float16 wlds[16][72];  // [outc][k], outc>=6 zero
  const int tx = threadIdx.x;
  for (int i = tx; i < 1024; i += 256) {
    const int c = i >> 6;
    const int k = i & 63;
    float v = 0.f;
    if (c < 3) v = Wl2[k * 3 + c];
    else if (c < 6) v = Wr2[k * 3 + (c - 3)];
    wlds[c][k] = (_Float16)v;
  }
  __syncthreads();
  const int lane = tx & 63;
  const int wv = tx >> 6;
  const int lrow = lane & 15;
  const int g = lane >> 4;
  const int in_node = blockIdx.x * 64 + wv * 16 + lrow;

  f32x4 acc = (f32x4){0.f, 0.f, 0.f, 0.f};
#pragma unroll
  for (int kt = 0; kt < 2; ++kt) {
    half8 a;
    if (in_node < N)
      a = *(const half8*)&h[(size_t)in_node * HID + kt * 32 + g * 8];
    else
      a = (half8){0, 0, 0, 0, 0, 0, 0, 0};
    const half8 b = *(const half8*)&wlds[lrow][kt * 32 + g * 8];
    acc = __builtin_amdgcn_mfma_f32_16x16x32_f16(a, b, acc, 0, 0, 0);
  }
  const int outc = lrow;
  if (outc < 6) {
#pragma unroll
    for (int reg = 0; reg < 4; ++reg) {
      const int n = blockIdx.x * 64 + wv * 16 + g * 4 + reg;
      if (n < N) {
        if (outc < 3)
          pl[(size_t)n * 3 + outc] = acc[reg];
        else
          pr[(size_t)n * 3 + outc - 3] = acc[reg];
      }
    }
  }
}

// ---- final: gather pl over neighbors, log_softmax -------------------------
__global__ __launch_bounds__(256) void final_kernel(
    const int* __restrict__ row_off, const int* __restrict__ deg_i,
    const int* __restrict__ csr_src, const float* __restrict__ pl,
    const float* __restrict__ pr, const float* __restrict__ b2,
    float* __restrict__ out, int N) {
  const int stride = gridDim.x * blockDim.x;
  const float b20 = b2[0], b21 = b2[1], b22 = b2[2];
  for (int n = blockIdx.x * blockDim.x + threadIdx.x; n < N; n += stride) {
    const int start = row_off[n];
    const int dg = deg_i[n];
    float s0 = 0.f, s1 = 0.f, s2 = 0.f;
    for (int r = 0; r < dg; ++r) {
      const int s = csr_src[start + r];
      s0 += pl[(size_t)s * 3 + 0];
      s1 += pl[(size_t)s * 3 + 1];
      s2 += pl[(size_t)s * 3 + 2];
    }
    const float dinv = 1.0f / fmaxf((float)dg, 1.0f);
    const float v0 = s0 * dinv + pr[(size_t)n * 3 + 0] + b20;
    const float v1 = s1 * dinv + pr[(size_t)n * 3 + 1] + b21;
    const float v2 = s2 * dinv + pr[(size_t)n * 3 + 2] + b22;
    const float m = fmaxf(fmaxf(v0, v1), v2);
    const float e0 = __expf(v0 - m), e1 = __expf(v1 - m), e2 = __expf(v2 - m);
    const float lse = __logf(e0 + e1 + e2);
    out[(size_t)n * 3 + 0] = v0 - m - lse;
    out[(size_t)n * 3 + 1] = v1 - m - lse;
    out[(size_t)n * 3 + 2] = v2 - m - lse;
  }
}

extern "C" void kernel_launch(void* const* d_in, const int* in_sizes, int n_in,
                              void* d_out, int out_size, void* d_ws,
                              size_t ws_size, hipStream_t stream) {
  const float* x = (const float*)d_in[0];
  const int* ei = (const int*)d_in[1];  // int32 (JAX x64 disabled)
  const float* Wl1 = (const float*)d_in[2];
  const float* Wr1 = (const float*)d_in[3];
  const float* b1 = (const float*)d_in[4];
  const float* Wl2 = (const float*)d_in[5];
  const float* Wr2 = (const float*)d_in[6];
  const float* b2 = (const float*)d_in[7];
  float* out = (float*)d_out;

  const int N = in_sizes[0] / IN_DIM;
  const int E = in_sizes[1] / 2;
  const int nb1 = (N + SCAN_B - 1) / SCAN_B;

  int* wsI = (int*)d_ws;
  int* deg_i = wsI;              // [N]
  int* row_off = deg_i + N;      // [N]
  int* incl = row_off + N;       // [N]
  int* bsum = incl + N;          // [SCAN_B]
  int* boff = bsum + SCAN_B;     // [SCAN_B]
  int* eoff = boff + SCAN_B;     // [E]
  int* csr_src = eoff + E;       // [E]
  _Float16* wcatT = (_Float16*)(csr_src + E);   // [128*128] f16
  _Float16* xW = wcatT + 128 * 128;             // [N*64] f16
  _Float16* xWr = xW + (size_t)N * HID;         // [N*64] f16
  _Float16* h = xWr + (size_t)N * HID;          // [N*64] f16
  float* pl = (float*)(h + (size_t)N * HID);    // [N*3]
  float* pr = pl + (size_t)N * 3;               // [N*3]

  hipMemsetAsync(deg_i, 0, (size_t)N * sizeof(int), stream);

  wconv_kernel<<<64, 256, 0, stream>>>(Wl1, Wr1, wcatT);
  proj1_kernel<<<(N + BM - 1) / BM, 256, 0, stream>>>(x, wcatT, xW, xWr, N);
  count_kernel<<<(E + 255) / 256, 256, 0, stream>>>(ei, deg_i, eoff, E);
  scan1_kernel<<<nb1, SCAN_B, 0, stream>>>(deg_i, incl, bsum, N);
  scan2_kernel<<<1, SCAN_B, 0, stream>>>(bsum, boff, nb1);
  scan3_kernel<<<(N + 255) / 256, 256, 0, stream>>>(incl, deg_i, boff, row_off,
                                                    N);
  fill_kernel<<<(E + 255) / 256, 256, 0, stream>>>(ei, row_off, eoff, csr_src,
                                                   E);
  gather1_kernel<<<2048, 256, 0, stream>>>(row_off, deg_i, csr_src, xW, xWr,
                                           b1, h, N);
  proj2_kernel<<<(N + 63) / 64, 256, 0, stream>>>(h, Wl2, Wr2, pl, pr, N);
  final_kernel<<<(N + 255) / 256, 256, 0, stream>>>(row_off, deg_i, csr_src,
                                                    pl, pr, b2, out, N);
}

// Round 12
// 140.584 us; speedup vs baseline: 1.5353x; 1.0031x over previous
//
#include <hip/hip_runtime.h>
#include <hip/hip_bf16.h>

#define IN_DIM 128
#define HID 64
#define BM 64
#define SCAN_B 1024
#define WSTR 136  // f16 LDS row stride (pad: 2-way bank access, free)

using half8 = __attribute__((ext_vector_type(8))) _Float16;
using f32x4 = __attribute__((ext_vector_type(4))) float;

// ---- zero: deg_i[N] = 0 (own kernel; rocclr small-fill path took 40us) ----
__global__ __launch_bounds__(256) void zero_kernel(int4* __restrict__ p,
                                                   int n4) {
  const int i = blockIdx.x * blockDim.x + threadIdx.x;
  if (i < n4) p[i] = (int4){0, 0, 0, 0};
}

// ---- wconv: pre-convert [Wl1|Wr1] to f16, transposed: wcatT[col][k] -------
__global__ __launch_bounds__(256) void wconv_kernel(
    const float* __restrict__ Wl, const float* __restrict__ Wr,
    _Float16* __restrict__ wcatT) {
  const int i = blockIdx.x * 256 + threadIdx.x;  // 64 blocks -> 16384 elems
  const int col = i >> 7;
  const int k = i & 127;
  const float v = (col < 64) ? Wl[k * HID + col] : Wr[k * HID + col - 64];
  wcatT[col * 128 + k] = (_Float16)v;
}

// ---- proj1: [xW | xWr] = x @ [Wl1 | Wr1]  via f16 MFMA, fp32 accumulate ---
__global__ __launch_bounds__(256) void proj1_kernel(
    const float* __restrict__ x, const _Float16* __restrict__ wcatT,
    _Float16* __restrict__ xW, _Float16* __restrict__ xWr, int N) {
  __shared__ _Float16 wsT[128][WSTR];  // [col][k]   34816 B
  __shared__ _Float16 xsT[64][WSTR];   // [node][k]  17408 B
  const int tx = threadIdx.x;
  const int n0 = blockIdx.x * BM;

  // ---- stage W^T: 2048 half8, 8 per thread (pre-converted f16) ----
#pragma unroll
  for (int it = 0; it < 8; ++it) {
    const int e8 = it * 256 + tx;
    const int col = e8 >> 4;
    const int k8 = (e8 & 15) * 8;
    *(half8*)&wsT[col][k8] = *(const half8*)&wcatT[col * 128 + k8];
  }

  // ---- stage x tile: node = tx>>2, k-quarter q = tx&3 (32 k each) ----
  {
    const int node = tx >> 2;
    const int q = tx & 3;
    const int gn = n0 + node;
    if (gn < N) {
      const float4* xp = (const float4*)&x[(size_t)gn * IN_DIM + q * 32];
#pragma unroll
      for (int j = 0; j < 4; ++j) {
        const float4 u = xp[2 * j];
        const float4 v = xp[2 * j + 1];
        half8 h;
        h[0] = (_Float16)u.x; h[1] = (_Float16)u.y;
        h[2] = (_Float16)u.z; h[3] = (_Float16)u.w;
        h[4] = (_Float16)v.x; h[5] = (_Float16)v.y;
        h[6] = (_Float16)v.z; h[7] = (_Float16)v.w;
        *(half8*)&xsT[node][q * 32 + j * 8] = h;
      }
    } else {
      const half8 hz = {0, 0, 0, 0, 0, 0, 0, 0};
#pragma unroll
      for (int j = 0; j < 4; ++j) *(half8*)&xsT[node][q * 32 + j * 8] = hz;
    }
  }
  __syncthreads();

  const int lane = tx & 63;
  const int wv = tx >> 6;
  const int lrow = lane & 15;
  const int g = lane >> 4;

  f32x4 acc[8];
#pragma unroll
  for (int ct = 0; ct < 8; ++ct) acc[ct] = (f32x4){0.f, 0.f, 0.f, 0.f};

#pragma unroll
  for (int kt = 0; kt < 4; ++kt) {
    const half8 a = *(const half8*)&xsT[wv * 16 + lrow][kt * 32 + g * 8];
#pragma unroll
    for (int ct = 0; ct < 8; ++ct) {
      const half8 b = *(const half8*)&wsT[ct * 16 + lrow][kt * 32 + g * 8];
      acc[ct] = __builtin_amdgcn_mfma_f32_16x16x32_f16(a, b, acc[ct], 0, 0, 0);
    }
  }

  // ---- C write: col = ct*16 + lrow, node = wv*16 + g*4 + reg ----
#pragma unroll
  for (int ct = 0; ct < 8; ++ct) {
    const int col = ct * 16 + lrow;
#pragma unroll
    for (int reg = 0; reg < 4; ++reg) {
      const int node = n0 + wv * 16 + g * 4 + reg;
      if (node < N) {
        if (col < 64)
          xW[(size_t)node * HID + col] = (_Float16)acc[ct][reg];
        else
          xWr[(size_t)node * HID + col - 64] = (_Float16)acc[ct][reg];
      }
    }
  }
}

// ---- CSR build ------------------------------------------------------------
// count: degree histogram AND per-edge rank (atomicAdd return), coalesced.
__global__ __launch_bounds__(256) void count_kernel(const int* __restrict__ ei,
                                                    int* __restrict__ deg_i,
                                                    int* __restrict__ eoff,
                                                    int E) {
  const int e = blockIdx.x * blockDim.x + threadIdx.x;
  if (e < E) eoff[e] = atomicAdd(&deg_i[ei[E + e]], 1);
}

__global__ __launch_bounds__(SCAN_B) void scan1_kernel(
    const int* __restrict__ in, int* __restrict__ incl, int* __restrict__ bsum,
    int n) {
  __shared__ int s[SCAN_B];
  const int t = threadIdx.x;
  const int i = blockIdx.x * SCAN_B + t;
  int v = (i < n) ? in[i] : 0;
  s[t] = v;
  for (int off = 1; off < SCAN_B; off <<= 1) {
    __syncthreads();
    const int a = (t >= off) ? s[t - off] : 0;
    __syncthreads();
    s[t] += a;
  }
  if (i < n) incl[i] = s[t];
  if (t == SCAN_B - 1) bsum[blockIdx.x] = s[t];
}

__global__ __launch_bounds__(SCAN_B) void scan2_kernel(
    const int* __restrict__ bsum, int* __restrict__ boff, int nb) {
  __shared__ int s[SCAN_B];
  const int t = threadIdx.x;
  const int v = (t < nb) ? bsum[t] : 0;
  s[t] = v;
  for (int off = 1; off < SCAN_B; off <<= 1) {
    __syncthreads();
    const int a = (t >= off) ? s[t - off] : 0;
    __syncthreads();
    s[t] += a;
  }
  if (t < nb) boff[t] = s[t] - v;  // exclusive
}

__global__ __launch_bounds__(256) void scan3_kernel(
    const int* __restrict__ incl, const int* __restrict__ deg_i,
    const int* __restrict__ boff, int* __restrict__ row_off, int n) {
  const int i = blockIdx.x * blockDim.x + threadIdx.x;
  if (i < n) row_off[i] = incl[i] - deg_i[i] + boff[i >> 10];
}

// fill: pos precomputed (row_off + eoff) -> no RMW chain; atomicExch store
// writes ~4B through to HBM (no per-XCD dirty-line amplification, R10 lesson).
__global__ __launch_bounds__(256) void fill_kernel(const int* __restrict__ ei,
                                                   const int* __restrict__ row_off,
                                                   const int* __restrict__ eoff,
                                                   int* __restrict__ csr_src,
                                                   int E) {
  const int e = blockIdx.x * blockDim.x + threadIdx.x;
  if (e < E) {
    const int s = ei[e];
    const int d = ei[E + e];
    atomicExch(&csr_src[row_off[d] + eoff[e]], s);
  }
}

// ---- gather1: h[n] = relu(mean_j xW[src] + xWr[n] + b1), f16 out ----------
__global__ __launch_bounds__(256) void gather1_kernel(
    const int* __restrict__ row_off, const int* __restrict__ deg_i,
    const int* __restrict__ csr_src, const _Float16* __restrict__ xW,
    const _Float16* __restrict__ xWr, const float* __restrict__ b1,
    _Float16* __restrict__ h, int N) {
  const int lane = threadIdx.x & 63;
  const float bb = b1[lane];
  const int wave = (blockIdx.x * blockDim.x + threadIdx.x) >> 6;
  const int nwaves = (gridDim.x * blockDim.x) >> 6;
  for (int n = wave; n < N; n += nwaves) {
    const int start = row_off[n];
    const int dg = deg_i[n];
    float a0 = 0.f, a1 = 0.f, a2 = 0.f, a3 = 0.f;
    int r = 0;
    for (; r + 3 < dg; r += 4) {
      const int s0 = csr_src[start + r];
      const int s1 = csr_src[start + r + 1];
      const int s2 = csr_src[start + r + 2];
      const int s3 = csr_src[start + r + 3];
      a0 += (float)xW[(size_t)s0 * HID + lane];
      a1 += (float)xW[(size_t)s1 * HID + lane];
      a2 += (float)xW[(size_t)s2 * HID + lane];
      a3 += (float)xW[(size_t)s3 * HID + lane];
    }
    for (; r < dg; ++r)
      a0 += (float)xW[(size_t)csr_src[start + r] * HID + lane];
    const float dinv = 1.0f / fmaxf((float)dg, 1.0f);
    const float hv =
        fmaxf(((a0 + a1) + (a2 + a3)) * dinv +
                  (float)xWr[(size_t)n * HID + lane] + bb,
              0.0f);
    h[(size_t)n * HID + lane] = (_Float16)hv;
  }
}

// ---- proj2: [pl|pr] = h @ [Wl2|Wr2]  via MFMA (cols padded 6->16) ---------
__global__ __launch_bounds__(256) void proj2_kernel(
    const _Float16* __restrict__ h, const float* __restrict__ Wl2,
    const float* __restrict__ Wr2, float* __restrict__ pl,
    float* __restrict__ pr, int N) {
  __shared__ _Float16 wlds[16][72];  // [outc][k], outc>=6 zero
  const int tx = threadIdx.x;
  for (int i = tx; i < 1024; i += 256) {
    const int c = i >> 6;
    const int k = i & 63;
    float v = 0.f;
    if (c < 3) v = Wl2[k * 3 + c];
    else if (c < 6) v = Wr2[k * 3 + (c - 3)];
    wlds[c][k] = (_Float16)v;
  }
  __syncthreads();
  const int lane = tx & 63;
  const int wv = tx >> 6;
  const int lrow = lane & 15;
  const int g = lane >> 4;
  const int in_node = blockIdx.x * 64 + wv * 16 + lrow;

  f32x4 acc = (f32x4){0.f, 0.f, 0.f, 0.f};
#pragma unroll
  for (int kt = 0; kt < 2; ++kt) {
    half8 a;
    if (in_node < N)
      a = *(const half8*)&h[(size_t)in_node * HID + kt * 32 + g * 8];
    else
      a = (half8){0, 0, 0, 0, 0, 0, 0, 0};
    const half8 b = *(const half8*)&wlds[lrow][kt * 32 + g * 8];
    acc = __builtin_amdgcn_mfma_f32_16x16x32_f16(a, b, acc, 0, 0, 0);
  }
  const int outc = lrow;
  if (outc < 6) {
#pragma unroll
    for (int reg = 0; reg < 4; ++reg) {
      const int n = blockIdx.x * 64 + wv * 16 + g * 4 + reg;
      if (n < N) {
        if (outc < 3)
          pl[(size_t)n * 3 + outc] = acc[reg];
        else
          pr[(size_t)n * 3 + outc - 3] = acc[reg];
      }
    }
  }
}

// ---- final: gather pl over neighbors, log_softmax -------------------------
__global__ __launch_bounds__(256) void final_kernel(
    const int* __restrict__ row_off, const int* __restrict__ deg_i,
    const int* __restrict__ csr_src, const float* __restrict__ pl,
    const float* __restrict__ pr, const float* __restrict__ b2,
    float* __restrict__ out, int N) {
  const int stride = gridDim.x * blockDim.x;
  const float b20 = b2[0], b21 = b2[1], b22 = b2[2];
  for (int n = blockIdx.x * blockDim.x + threadIdx.x; n < N; n += stride) {
    const int start = row_off[n];
    const int dg = deg_i[n];
    float s0 = 0.f, s1 = 0.f, s2 = 0.f;
    for (int r = 0; r < dg; ++r) {
      const int s = csr_src[start + r];
      s0 += pl[(size_t)s * 3 + 0];
      s1 += pl[(size_t)s * 3 + 1];
      s2 += pl[(size_t)s * 3 + 2];
    }
    const float dinv = 1.0f / fmaxf((float)dg, 1.0f);
    const float v0 = s0 * dinv + pr[(size_t)n * 3 + 0] + b20;
    const float v1 = s1 * dinv + pr[(size_t)n * 3 + 1] + b21;
    const float v2 = s2 * dinv + pr[(size_t)n * 3 + 2] + b22;
    const float m = fmaxf(fmaxf(v0, v1), v2);
    const float e0 = __expf(v0 - m), e1 = __expf(v1 - m), e2 = __expf(v2 - m);
    const float lse = __logf(e0 + e1 + e2);
    out[(size_t)n * 3 + 0] = v0 - m - lse;
    out[(size_t)n * 3 + 1] = v1 - m - lse;
    out[(size_t)n * 3 + 2] = v2 - m - lse;
  }
}

extern "C" void kernel_launch(void* const* d_in, const int* in_sizes, int n_in,
                              void* d_out, int out_size, void* d_ws,
                              size_t ws_size, hipStream_t stream) {
  const float* x = (const float*)d_in[0];
  const int* ei = (const int*)d_in[1];  // int32 (JAX x64 disabled)
  const float* Wl1 = (const float*)d_in[2];
  const float* Wr1 = (const float*)d_in[3];
  const float* b1 = (const float*)d_in[4];
  const float* Wl2 = (const float*)d_in[5];
  const float* Wr2 = (const float*)d_in[6];
  const float* b2 = (const float*)d_in[7];
  float* out = (float*)d_out;

  const int N = in_sizes[0] / IN_DIM;
  const int E = in_sizes[1] / 2;
  const int nb1 = (N + SCAN_B - 1) / SCAN_B;

  int* wsI = (int*)d_ws;
  int* deg_i = wsI;              // [N]  (16B aligned; zeroed by zero_kernel)
  int* row_off = deg_i + N;      // [N]
  int* incl = row_off + N;       // [N]
  int* bsum = incl + N;          // [SCAN_B]
  int* boff = bsum + SCAN_B;     // [SCAN_B]
  int* eoff = boff + SCAN_B;     // [E]
  int* csr_src = eoff + E;       // [E]
  _Float16* wcatT = (_Float16*)(csr_src + E);   // [128*128] f16
  _Float16* xW = wcatT + 128 * 128;             // [N*64] f16
  _Float16* xWr = xW + (size_t)N * HID;         // [N*64] f16
  _Float16* h = xWr + (size_t)N * HID;          // [N*64] f16
  float* pl = (float*)(h + (size_t)N * HID);    // [N*3]
  float* pr = pl + (size_t)N * 3;               // [N*3]

  const int n4 = (N + 3) / 4;  // deg_i int4 count (N=100000 -> exact)
  zero_kernel<<<(n4 + 255) / 256, 256, 0, stream>>>((int4*)deg_i, n4);
  wconv_kernel<<<64, 256, 0, stream>>>(Wl1, Wr1, wcatT);
  proj1_kernel<<<(N + BM - 1) / BM, 256, 0, stream>>>(x, wcatT, xW, xWr, N);
  count_kernel<<<(E + 255) / 256, 256, 0, stream>>>(ei, deg_i, eoff, E);
  scan1_kernel<<<nb1, SCAN_B, 0, stream>>>(deg_i, incl, bsum, N);
  scan2_kernel<<<1, SCAN_B, 0, stream>>>(bsum, boff, nb1);
  scan3_kernel<<<(N + 255) / 256, 256, 0, stream>>>(incl, deg_i, boff, row_off,
                                                    N);
  fill_kernel<<<(E + 255) / 256, 256, 0, stream>>>(ei, row_off, eoff, csr_src,
                                                   E);
  gather1_kernel<<<2048, 256, 0, stream>>>(row_off, deg_i, csr_src, xW, xWr,
                                           b1, h, N);
  proj2_kernel<<<(N + 63) / 64, 256, 0, stream>>>(h, Wl2, Wr2, pl, pr, N);
  final_kernel<<<(N + 255) / 256, 256, 0, stream>>>(row_off, deg_i, csr_src,
                                                    pl, pr, b2, out, N);
}

// Round 13
// 136.602 us; speedup vs baseline: 1.5801x; 1.0292x over previous
//
#include <hip/hip_runtime.h>
#include <hip/hip_bf16.h>

#define IN_DIM 128
#define HID 64
#define SCAN_B 1024
#define WSTR 136  // f16 LDS row stride (pad: 2-way bank access, free)

using half8 = __attribute__((ext_vector_type(8))) _Float16;
using f32x4 = __attribute__((ext_vector_type(4))) float;

// ---- init: zero deg_i AND convert [Wl1|Wr1] -> f16 wcatT (fused) ----------
__global__ __launch_bounds__(256) void init_kernel(
    const float* __restrict__ Wl, const float* __restrict__ Wr,
    _Float16* __restrict__ wcatT, int4* __restrict__ deg4, int n4) {
  const int i = blockIdx.x * 256 + threadIdx.x;
  if (i < 16384) {
    const int col = i >> 7;
    const int k = i & 127;
    const float v = (col < 64) ? Wl[k * HID + col] : Wr[k * HID + col - 64];
    wcatT[col * 128 + k] = (_Float16)v;
  }
  if (i < n4) deg4[i] = (int4){0, 0, 0, 0};
}

// ---- proj1: [xW | xWr] = x @ [Wl1 | Wr1]  via f16 MFMA, fp32 accumulate ---
// Persistent blocks: W^T staged ONCE, grid-stride loop over 64-node tiles.
__global__ __launch_bounds__(256) void proj1_kernel(
    const float* __restrict__ x, const _Float16* __restrict__ wcatT,
    _Float16* __restrict__ xW, _Float16* __restrict__ xWr, int N, int ntiles) {
  __shared__ _Float16 wsT[128][WSTR];  // [col][k]   34816 B
  __shared__ _Float16 xsT[64][WSTR];   // [node][k]  17408 B
  const int tx = threadIdx.x;

  // ---- stage W^T once: 2048 half8, 8 per thread ----
#pragma unroll
  for (int it = 0; it < 8; ++it) {
    const int e8 = it * 256 + tx;
    const int col = e8 >> 4;
    const int k8 = (e8 & 15) * 8;
    *(half8*)&wsT[col][k8] = *(const half8*)&wcatT[col * 128 + k8];
  }

  const int node = tx >> 2;       // x-stage map
  const int q = tx & 3;
  const int lane = tx & 63;
  const int wv = tx >> 6;
  const int lrow = lane & 15;
  const int g = lane >> 4;

  __syncthreads();

#pragma unroll 1
  for (int tile = blockIdx.x; tile < ntiles; tile += gridDim.x) {
    const int n0 = tile * 64;
    // ---- stage x tile ----
    {
      const int gn = n0 + node;
      if (gn < N) {
        const float4* xp = (const float4*)&x[(size_t)gn * IN_DIM + q * 32];
#pragma unroll
        for (int j = 0; j < 4; ++j) {
          const float4 u = xp[2 * j];
          const float4 v = xp[2 * j + 1];
          half8 h;
          h[0] = (_Float16)u.x; h[1] = (_Float16)u.y;
          h[2] = (_Float16)u.z; h[3] = (_Float16)u.w;
          h[4] = (_Float16)v.x; h[5] = (_Float16)v.y;
          h[6] = (_Float16)v.z; h[7] = (_Float16)v.w;
          *(half8*)&xsT[node][q * 32 + j * 8] = h;
        }
      } else {
        const half8 hz = {0, 0, 0, 0, 0, 0, 0, 0};
#pragma unroll
        for (int j = 0; j < 4; ++j) *(half8*)&xsT[node][q * 32 + j * 8] = hz;
      }
    }
    __syncthreads();

    f32x4 acc[8];
#pragma unroll
    for (int ct = 0; ct < 8; ++ct) acc[ct] = (f32x4){0.f, 0.f, 0.f, 0.f};

#pragma unroll
    for (int kt = 0; kt < 4; ++kt) {
      const half8 a = *(const half8*)&xsT[wv * 16 + lrow][kt * 32 + g * 8];
#pragma unroll
      for (int ct = 0; ct < 8; ++ct) {
        const half8 b = *(const half8*)&wsT[ct * 16 + lrow][kt * 32 + g * 8];
        acc[ct] =
            __builtin_amdgcn_mfma_f32_16x16x32_f16(a, b, acc[ct], 0, 0, 0);
      }
    }

    // ---- C write: col = ct*16 + lrow, node = wv*16 + g*4 + reg ----
#pragma unroll
    for (int ct = 0; ct < 8; ++ct) {
      const int col = ct * 16 + lrow;
#pragma unroll
      for (int reg = 0; reg < 4; ++reg) {
        const int nn = n0 + wv * 16 + g * 4 + reg;
        if (nn < N) {
          if (col < 64)
            xW[(size_t)nn * HID + col] = (_Float16)acc[ct][reg];
          else
            xWr[(size_t)nn * HID + col - 64] = (_Float16)acc[ct][reg];
        }
      }
    }
    __syncthreads();  // xsT reads done before next tile's stage
  }
}

// ---- CSR build ------------------------------------------------------------
__global__ __launch_bounds__(256) void count_kernel(const int* __restrict__ ei,
                                                    int* __restrict__ deg_i,
                                                    int* __restrict__ eoff,
                                                    int E) {
  const int e = blockIdx.x * blockDim.x + threadIdx.x;
  if (e < E) eoff[e] = atomicAdd(&deg_i[ei[E + e]], 1);
}

__global__ __launch_bounds__(SCAN_B) void scan1_kernel(
    const int* __restrict__ in, int* __restrict__ incl, int* __restrict__ bsum,
    int n) {
  __shared__ int s[SCAN_B];
  const int t = threadIdx.x;
  const int i = blockIdx.x * SCAN_B + t;
  int v = (i < n) ? in[i] : 0;
  s[t] = v;
  for (int off = 1; off < SCAN_B; off <<= 1) {
    __syncthreads();
    const int a = (t >= off) ? s[t - off] : 0;
    __syncthreads();
    s[t] += a;
  }
  if (i < n) incl[i] = s[t];
  if (t == SCAN_B - 1) bsum[blockIdx.x] = s[t];
}

__global__ __launch_bounds__(SCAN_B) void scan2_kernel(
    const int* __restrict__ bsum, int* __restrict__ boff, int nb) {
  __shared__ int s[SCAN_B];
  const int t = threadIdx.x;
  const int v = (t < nb) ? bsum[t] : 0;
  s[t] = v;
  for (int off = 1; off < SCAN_B; off <<= 1) {
    __syncthreads();
    const int a = (t >= off) ? s[t - off] : 0;
    __syncthreads();
    s[t] += a;
  }
  if (t < nb) boff[t] = s[t] - v;  // exclusive
}

__global__ __launch_bounds__(256) void scan3_kernel(
    const int* __restrict__ incl, const int* __restrict__ deg_i,
    const int* __restrict__ boff, int* __restrict__ row_off, int n) {
  const int i = blockIdx.x * blockDim.x + threadIdx.x;
  if (i < n) row_off[i] = incl[i] - deg_i[i] + boff[i >> 10];
}

// fill: pos precomputed; atomicExch store avoids per-XCD dirty-line
// amplification (R10 counter evidence: plain scatter stores -> 15x WRITE).
__global__ __launch_bounds__(256) void fill_kernel(
    const int* __restrict__ ei, const int* __restrict__ row_off,
    const int* __restrict__ eoff, int* __restrict__ csr_src, int E) {
  const int e = blockIdx.x * blockDim.x + threadIdx.x;
  if (e < E) {
    const int s = ei[e];
    const int d = ei[E + e];
    atomicExch(&csr_src[row_off[d] + eoff[e]], s);
  }
}

// ---- gather1: h[n] = relu(mean_j xW[src] + xWr[n] + b1), f16 out ----------
__global__ __launch_bounds__(256) void gather1_kernel(
    const int* __restrict__ row_off, const int* __restrict__ deg_i,
    const int* __restrict__ csr_src, const _Float16* __restrict__ xW,
    const _Float16* __restrict__ xWr, const float* __restrict__ b1,
    _Float16* __restrict__ h, int N) {
  const int lane = threadIdx.x & 63;
  const float bb = b1[lane];
  const int wave = (blockIdx.x * blockDim.x + threadIdx.x) >> 6;
  const int nwaves = (gridDim.x * blockDim.x) >> 6;
  for (int n = wave; n < N; n += nwaves) {
    const int start = row_off[n];
    const int dg = deg_i[n];
    float a0 = 0.f, a1 = 0.f, a2 = 0.f, a3 = 0.f;
    int r = 0;
    for (; r + 3 < dg; r += 4) {
      const int s0 = csr_src[start + r];
      const int s1 = csr_src[start + r + 1];
      const int s2 = csr_src[start + r + 2];
      const int s3 = csr_src[start + r + 3];
      a0 += (float)xW[(size_t)s0 * HID + lane];
      a1 += (float)xW[(size_t)s1 * HID + lane];
      a2 += (float)xW[(size_t)s2 * HID + lane];
      a3 += (float)xW[(size_t)s3 * HID + lane];
    }
    for (; r < dg; ++r)
      a0 += (float)xW[(size_t)csr_src[start + r] * HID + lane];
    const float dinv = 1.0f / fmaxf((float)dg, 1.0f);
    const float hv =
        fmaxf(((a0 + a1) + (a2 + a3)) * dinv +
                  (float)xWr[(size_t)n * HID + lane] + bb,
              0.0f);
    h[(size_t)n * HID + lane] = (_Float16)hv;
  }
}

// ---- proj2: [pl|pr] = h @ [Wl2|Wr2]  via MFMA, persistent tiles -----------
__global__ __launch_bounds__(256) void proj2_kernel(
    const _Float16* __restrict__ h, const float* __restrict__ Wl2,
    const float* __restrict__ Wr2, float* __restrict__ pl,
    float* __restrict__ pr, int N, int ntiles) {
  __shared__ _Float16 wlds[16][72];  // [outc][k], outc>=6 zero
  const int tx = threadIdx.x;
  for (int i = tx; i < 1024; i += 256) {
    const int c = i >> 6;
    const int k = i & 63;
    float v = 0.f;
    if (c < 3) v = Wl2[k * 3 + c];
    else if (c < 6) v = Wr2[k * 3 + (c - 3)];
    wlds[c][k] = (_Float16)v;
  }
  __syncthreads();
  const int lane = tx & 63;
  const int wv = tx >> 6;
  const int lrow = lane & 15;
  const int g = lane >> 4;

#pragma unroll 1
  for (int tile = blockIdx.x; tile < ntiles; tile += gridDim.x) {
    const int base = tile * 64;
    const int in_node = base + wv * 16 + lrow;
    f32x4 acc = (f32x4){0.f, 0.f, 0.f, 0.f};
#pragma unroll
    for (int kt = 0; kt < 2; ++kt) {
      half8 a;
      if (in_node < N)
        a = *(const half8*)&h[(size_t)in_node * HID + kt * 32 + g * 8];
      else
        a = (half8){0, 0, 0, 0, 0, 0, 0, 0};
      const half8 b = *(const half8*)&wlds[lrow][kt * 32 + g * 8];
      acc = __builtin_amdgcn_mfma_f32_16x16x32_f16(a, b, acc, 0, 0, 0);
    }
    if (lrow < 6) {
#pragma unroll
      for (int reg = 0; reg < 4; ++reg) {
        const int n = base + wv * 16 + g * 4 + reg;
        if (n < N) {
          if (lrow < 3)
            pl[(size_t)n * 3 + lrow] = acc[reg];
          else
            pr[(size_t)n * 3 + lrow - 3] = acc[reg];
        }
      }
    }
  }
}

// ---- final: gather pl over neighbors, log_softmax (2-row MLP unroll) ------
__global__ __launch_bounds__(256) void final_kernel(
    const int* __restrict__ row_off, const int* __restrict__ deg_i,
    const int* __restrict__ csr_src, const float* __restrict__ pl,
    const float* __restrict__ pr, const float* __restrict__ b2,
    float* __restrict__ out, int N) {
  const int stride = gridDim.x * blockDim.x;
  const float b20 = b2[0], b21 = b2[1], b22 = b2[2];
  for (int n = blockIdx.x * blockDim.x + threadIdx.x; n < N; n += stride) {
    const int start = row_off[n];
    const int dg = deg_i[n];
    float s0 = 0.f, s1 = 0.f, s2 = 0.f;
    float t0 = 0.f, t1 = 0.f, t2 = 0.f;
    int r = 0;
    for (; r + 1 < dg; r += 2) {
      const int sa = csr_src[start + r];
      const int sb = csr_src[start + r + 1];
      s0 += pl[(size_t)sa * 3 + 0];
      s1 += pl[(size_t)sa * 3 + 1];
      s2 += pl[(size_t)sa * 3 + 2];
      t0 += pl[(size_t)sb * 3 + 0];
      t1 += pl[(size_t)sb * 3 + 1];
      t2 += pl[(size_t)sb * 3 + 2];
    }
    if (r < dg) {
      const int sa = csr_src[start + r];
      s0 += pl[(size_t)sa * 3 + 0];
      s1 += pl[(size_t)sa * 3 + 1];
      s2 += pl[(size_t)sa * 3 + 2];
    }
    const float dinv = 1.0f / fmaxf((float)dg, 1.0f);
    const float v0 = (s0 + t0) * dinv + pr[(size_t)n * 3 + 0] + b20;
    const float v1 = (s1 + t1) * dinv + pr[(size_t)n * 3 + 1] + b21;
    const float v2 = (s2 + t2) * dinv + pr[(size_t)n * 3 + 2] + b22;
    const float m = fmaxf(fmaxf(v0, v1), v2);
    const float e0 = __expf(v0 - m), e1 = __expf(v1 - m), e2 = __expf(v2 - m);
    const float lse = __logf(e0 + e1 + e2);
    out[(size_t)n * 3 + 0] = v0 - m - lse;
    out[(size_t)n * 3 + 1] = v1 - m - lse;
    out[(size_t)n * 3 + 2] = v2 - m - lse;
  }
}

extern "C" void kernel_launch(void* const* d_in, const int* in_sizes, int n_in,
                              void* d_out, int out_size, void* d_ws,
                              size_t ws_size, hipStream_t stream) {
  const float* x = (const float*)d_in[0];
  const int* ei = (const int*)d_in[1];  // int32 (JAX x64 disabled)
  const float* Wl1 = (const float*)d_in[2];
  const float* Wr1 = (const float*)d_in[3];
  const float* b1 = (const float*)d_in[4];
  const float* Wl2 = (const float*)d_in[5];
  const float* Wr2 = (const float*)d_in[6];
  const float* b2 = (const float*)d_in[7];
  float* out = (float*)d_out;

  const int N = in_sizes[0] / IN_DIM;
  const int E = in_sizes[1] / 2;
  const int nb1 = (N + SCAN_B - 1) / SCAN_B;
  const int ntiles = (N + 63) / 64;

  int* wsI = (int*)d_ws;
  int* deg_i = wsI;              // [N]  (16B aligned)
  int* row_off = deg_i + N;      // [N]
  int* incl = row_off + N;       // [N]
  int* bsum = incl + N;          // [SCAN_B]
  int* boff = bsum + SCAN_B;     // [SCAN_B]
  int* eoff = boff + SCAN_B;     // [E]
  int* csr_src = eoff + E;       // [E]
  _Float16* wcatT = (_Float16*)(csr_src + E);   // [128*128] f16
  _Float16* xW = wcatT + 128 * 128;             // [N*64] f16
  _Float16* xWr = xW + (size_t)N * HID;         // [N*64] f16
  _Float16* h = xWr + (size_t)N * HID;          // [N*64] f16
  float* pl = (float*)(h + (size_t)N * HID);    // [N*3]
  float* pr = pl + (size_t)N * 3;               // [N*3]

  const int n4 = (N + 3) / 4;
  const int initg = (max(n4, 16384) + 255) / 256;
  init_kernel<<<initg, 256, 0, stream>>>(Wl1, Wr1, wcatT, (int4*)deg_i, n4);
  proj1_kernel<<<768, 256, 0, stream>>>(x, wcatT, xW, xWr, N, ntiles);
  count_kernel<<<(E + 255) / 256, 256, 0, stream>>>(ei, deg_i, eoff, E);
  scan1_kernel<<<nb1, SCAN_B, 0, stream>>>(deg_i, incl, bsum, N);
  scan2_kernel<<<1, SCAN_B, 0, stream>>>(bsum, boff, nb1);
  scan3_kernel<<<(N + 255) / 256, 256, 0, stream>>>(incl, deg_i, boff, row_off,
                                                    N);
  fill_kernel<<<(E + 255) / 256, 256, 0, stream>>>(ei, row_off, eoff, csr_src,
                                                   E);
  gather1_kernel<<<2048, 256, 0, stream>>>(row_off, deg_i, csr_src, xW, xWr,
                                           b1, h, N);
  proj2_kernel<<<512, 256, 0, stream>>>(h, Wl2, Wr2, pl, pr, N, ntiles);
  final_kernel<<<(N + 255) / 256, 256, 0, stream>>>(row_off, deg_i, csr_src,
                                                    pl, pr, b2, out, N);
}

// Round 14
// 131.591 us; speedup vs baseline: 1.6402x; 1.0381x over previous
//
#include <hip/hip_runtime.h>
#include <hip/hip_bf16.h>

#define IN_DIM 128
#define HID 64
#define SCAN_B 1024
#define WSTR 136  // f16 LDS row stride (pad: 2-way bank access, free)
#define PB 768    // proj1 blocks inside proj1_count_kernel

using half8 = __attribute__((ext_vector_type(8))) _Float16;
using f32x4 = __attribute__((ext_vector_type(4))) float;

// ---- init: zero deg_i AND convert [Wl1|Wr1] -> f16 wcatT (fused) ----------
__global__ __launch_bounds__(256) void init_kernel(
    const float* __restrict__ Wl, const float* __restrict__ Wr,
    _Float16* __restrict__ wcatT, int4* __restrict__ deg4, int n4) {
  const int i = blockIdx.x * 256 + threadIdx.x;
  if (i < 16384) {
    const int col = i >> 7;
    const int k = i & 127;
    const float v = (col < 64) ? Wl[k * HID + col] : Wr[k * HID + col - 64];
    wcatT[col * 128 + k] = (_Float16)v;
  }
  if (i < n4) deg4[i] = (int4){0, 0, 0, 0};
}

// ---- proj1 (blocks 0..PB-1) PARALLEL WITH count (blocks PB..) -------------
// proj1: [xW|xWr] = x @ [Wl1|Wr1] via f16 MFMA, persistent 64-node tiles.
// count: eoff[e] = rank of edge e at its dst (atomicAdd return), coalesced.
__global__ __launch_bounds__(256) void proj1_count_kernel(
    const float* __restrict__ x, const _Float16* __restrict__ wcatT,
    _Float16* __restrict__ xW, _Float16* __restrict__ xWr, int N, int ntiles,
    const int* __restrict__ ei, int* __restrict__ deg_i,
    int* __restrict__ eoff, int E) {
  const int tx = threadIdx.x;
  if (blockIdx.x >= PB) {
    const int nb = gridDim.x - PB;
    for (int e = (blockIdx.x - PB) * 256 + tx; e < E; e += nb * 256)
      eoff[e] = atomicAdd(&deg_i[ei[E + e]], 1);
    return;
  }
  __shared__ _Float16 wsT[128][WSTR];  // [col][k]
  __shared__ _Float16 xsT[64][WSTR];   // [node][k]

  // ---- stage W^T once ----
#pragma unroll
  for (int it = 0; it < 8; ++it) {
    const int e8 = it * 256 + tx;
    const int col = e8 >> 4;
    const int k8 = (e8 & 15) * 8;
    *(half8*)&wsT[col][k8] = *(const half8*)&wcatT[col * 128 + k8];
  }

  const int node = tx >> 2;
  const int q = tx & 3;
  const int lane = tx & 63;
  const int wv = tx >> 6;
  const int lrow = lane & 15;
  const int g = lane >> 4;

  __syncthreads();

#pragma unroll 1
  for (int tile = blockIdx.x; tile < ntiles; tile += PB) {
    const int n0 = tile * 64;
    {
      const int gn = n0 + node;
      if (gn < N) {
        const float4* xp = (const float4*)&x[(size_t)gn * IN_DIM + q * 32];
#pragma unroll
        for (int j = 0; j < 4; ++j) {
          const float4 u = xp[2 * j];
          const float4 v = xp[2 * j + 1];
          half8 h;
          h[0] = (_Float16)u.x; h[1] = (_Float16)u.y;
          h[2] = (_Float16)u.z; h[3] = (_Float16)u.w;
          h[4] = (_Float16)v.x; h[5] = (_Float16)v.y;
          h[6] = (_Float16)v.z; h[7] = (_Float16)v.w;
          *(half8*)&xsT[node][q * 32 + j * 8] = h;
        }
      } else {
        const half8 hz = {0, 0, 0, 0, 0, 0, 0, 0};
#pragma unroll
        for (int j = 0; j < 4; ++j) *(half8*)&xsT[node][q * 32 + j * 8] = hz;
      }
    }
    __syncthreads();

    f32x4 acc[8];
#pragma unroll
    for (int ct = 0; ct < 8; ++ct) acc[ct] = (f32x4){0.f, 0.f, 0.f, 0.f};

#pragma unroll
    for (int kt = 0; kt < 4; ++kt) {
      const half8 a = *(const half8*)&xsT[wv * 16 + lrow][kt * 32 + g * 8];
#pragma unroll
      for (int ct = 0; ct < 8; ++ct) {
        const half8 b = *(const half8*)&wsT[ct * 16 + lrow][kt * 32 + g * 8];
        acc[ct] =
            __builtin_amdgcn_mfma_f32_16x16x32_f16(a, b, acc[ct], 0, 0, 0);
      }
    }

#pragma unroll
    for (int ct = 0; ct < 8; ++ct) {
      const int col = ct * 16 + lrow;
#pragma unroll
      for (int reg = 0; reg < 4; ++reg) {
        const int nn = n0 + wv * 16 + g * 4 + reg;
        if (nn < N) {
          if (col < 64)
            xW[(size_t)nn * HID + col] = (_Float16)acc[ct][reg];
          else
            xWr[(size_t)nn * HID + col - 64] = (_Float16)acc[ct][reg];
        }
      }
    }
    __syncthreads();
  }
}

// ---- scan1: per-chunk inclusive scan of deg (1024-chunks) -----------------
__global__ __launch_bounds__(SCAN_B) void scan1_kernel(
    const int* __restrict__ in, int* __restrict__ incl, int* __restrict__ bsum,
    int n) {
  __shared__ int s[SCAN_B];
  const int t = threadIdx.x;
  const int i = blockIdx.x * SCAN_B + t;
  int v = (i < n) ? in[i] : 0;
  s[t] = v;
  for (int off = 1; off < SCAN_B; off <<= 1) {
    __syncthreads();
    const int a = (t >= off) ? s[t - off] : 0;
    __syncthreads();
    s[t] += a;
  }
  if (i < n) incl[i] = s[t];
  if (t == SCAN_B - 1) bsum[blockIdx.x] = s[t];
}

// ---- scan23: row_off[i] = incl[i] - deg[i] + sum(bsum[0..i>>10)) ----------
// Each 256-thread block spans ONE 1024-chunk (chunk = blockIdx>>2); the
// chunk offset is a <=98-element block reduction of bsum — scan2 deleted.
__global__ __launch_bounds__(256) void scan23_kernel(
    const int* __restrict__ incl, const int* __restrict__ deg_i,
    const int* __restrict__ bsum, int* __restrict__ row_off, int n) {
  __shared__ int sred[256];
  const int t = threadIdx.x;
  const int chunk = blockIdx.x >> 2;
  sred[t] = (t < chunk) ? bsum[t] : 0;
  __syncthreads();
#pragma unroll
  for (int off = 128; off >= 1; off >>= 1) {
    if (t < off) sred[t] += sred[t + off];
    __syncthreads();
  }
  const int boff = sred[0];
  const int i = blockIdx.x * 256 + t;
  if (i < n) row_off[i] = incl[i] - deg_i[i] + boff;
}

// fill: pos precomputed; atomicExch store avoids per-XCD dirty-line
// amplification (R10 counter evidence: plain scatter stores -> 15x WRITE).
__global__ __launch_bounds__(256) void fill_kernel(
    const int* __restrict__ ei, const int* __restrict__ row_off,
    const int* __restrict__ eoff, int* __restrict__ csr_src, int E) {
  const int e = blockIdx.x * blockDim.x + threadIdx.x;
  if (e < E) {
    const int s = ei[e];
    const int d = ei[E + e];
    atomicExch(&csr_src[row_off[d] + eoff[e]], s);
  }
}

// ---- layer1: gather+relu+proj2 fused. Wave computes 16 nodes' h rows into
// LDS, then runs the 64->6 MFMA off LDS. h never touches global. ------------
__global__ __launch_bounds__(256) void layer1_kernel(
    const int* __restrict__ row_off, const int* __restrict__ deg_i,
    const int* __restrict__ csr_src, const _Float16* __restrict__ xW,
    const _Float16* __restrict__ xWr, const float* __restrict__ b1,
    const float* __restrict__ Wl2, const float* __restrict__ Wr2,
    float* __restrict__ pl, float* __restrict__ pr, int N, int ntiles) {
  __shared__ _Float16 wlds[16][72];  // [outc][k], outc>=6 zero
  __shared__ _Float16 hlds[64][72];  // [node_local][col]
  const int tx = threadIdx.x;
  for (int i = tx; i < 1024; i += 256) {
    const int c = i >> 6;
    const int k = i & 63;
    float v = 0.f;
    if (c < 3) v = Wl2[k * 3 + c];
    else if (c < 6) v = Wr2[k * 3 + (c - 3)];
    wlds[c][k] = (_Float16)v;
  }
  const int lane = tx & 63;
  const int wv = tx >> 6;
  const int lrow = lane & 15;
  const int g = lane >> 4;
  const float bb = b1[lane];
  __syncthreads();

#pragma unroll 1
  for (int tile = blockIdx.x; tile < ntiles; tile += gridDim.x) {
    const int base = tile * 64;
    // ---- phase 1: wave wv gathers nodes base+wv*16 .. +15 ----
#pragma unroll 1
    for (int idx = 0; idx < 16; ++idx) {
      const int n = base + wv * 16 + idx;
      float hv = 0.f;
      if (n < N) {
        const int start = row_off[n];
        const int dg = deg_i[n];
        float a0 = 0.f, a1 = 0.f, a2 = 0.f, a3 = 0.f;
        int r = 0;
        for (; r + 3 < dg; r += 4) {
          const int s0 = csr_src[start + r];
          const int s1 = csr_src[start + r + 1];
          const int s2 = csr_src[start + r + 2];
          const int s3 = csr_src[start + r + 3];
          a0 += (float)xW[(size_t)s0 * HID + lane];
          a1 += (float)xW[(size_t)s1 * HID + lane];
          a2 += (float)xW[(size_t)s2 * HID + lane];
          a3 += (float)xW[(size_t)s3 * HID + lane];
        }
        for (; r < dg; ++r)
          a0 += (float)xW[(size_t)csr_src[start + r] * HID + lane];
        const float dinv = 1.0f / fmaxf((float)dg, 1.0f);
        hv = fmaxf(((a0 + a1) + (a2 + a3)) * dinv +
                       (float)xWr[(size_t)n * HID + lane] + bb,
                   0.0f);
      }
      hlds[wv * 16 + idx][lane] = (_Float16)hv;
    }
    __syncthreads();
    // ---- phase 2: 64->6 projection off LDS (2 MFMA per wave) ----
    f32x4 acc = (f32x4){0.f, 0.f, 0.f, 0.f};
#pragma unroll
    for (int kt = 0; kt < 2; ++kt) {
      const half8 a = *(const half8*)&hlds[wv * 16 + lrow][kt * 32 + g * 8];
      const half8 b = *(const half8*)&wlds[lrow][kt * 32 + g * 8];
      acc = __builtin_amdgcn_mfma_f32_16x16x32_f16(a, b, acc, 0, 0, 0);
    }
    if (lrow < 6) {
#pragma unroll
      for (int reg = 0; reg < 4; ++reg) {
        const int n = base + wv * 16 + g * 4 + reg;
        if (n < N) {
          if (lrow < 3)
            pl[(size_t)n * 3 + lrow] = acc[reg];
          else
            pr[(size_t)n * 3 + lrow - 3] = acc[reg];
        }
      }
    }
    __syncthreads();  // hlds reads done before next tile's writes
  }
}

// ---- final: gather pl over neighbors, log_softmax (2-row unroll) ----------
__global__ __launch_bounds__(256) void final_kernel(
    const int* __restrict__ row_off, const int* __restrict__ deg_i,
    const int* __restrict__ csr_src, const float* __restrict__ pl,
    const float* __restrict__ pr, const float* __restrict__ b2,
    float* __restrict__ out, int N) {
  const int stride = gridDim.x * blockDim.x;
  const float b20 = b2[0], b21 = b2[1], b22 = b2[2];
  for (int n = blockIdx.x * blockDim.x + threadIdx.x; n < N; n += stride) {
    const int start = row_off[n];
    const int dg = deg_i[n];
    float s0 = 0.f, s1 = 0.f, s2 = 0.f;
    float t0 = 0.f, t1 = 0.f, t2 = 0.f;
    int r = 0;
    for (; r + 1 < dg; r += 2) {
      const int sa = csr_src[start + r];
      const int sb = csr_src[start + r + 1];
      s0 += pl[(size_t)sa * 3 + 0];
      s1 += pl[(size_t)sa * 3 + 1];
      s2 += pl[(size_t)sa * 3 + 2];
      t0 += pl[(size_t)sb * 3 + 0];
      t1 += pl[(size_t)sb * 3 + 1];
      t2 += pl[(size_t)sb * 3 + 2];
    }
    if (r < dg) {
      const int sa = csr_src[start + r];
      s0 += pl[(size_t)sa * 3 + 0];
      s1 += pl[(size_t)sa * 3 + 1];
      s2 += pl[(size_t)sa * 3 + 2];
    }
    const float dinv = 1.0f / fmaxf((float)dg, 1.0f);
    const float v0 = (s0 + t0) * dinv + pr[(size_t)n * 3 + 0] + b20;
    const float v1 = (s1 + t1) * dinv + pr[(size_t)n * 3 + 1] + b21;
    const float v2 = (s2 + t2) * dinv + pr[(size_t)n * 3 + 2] + b22;
    const float m = fmaxf(fmaxf(v0, v1), v2);
    const float e0 = __expf(v0 - m), e1 = __expf(v1 - m), e2 = __expf(v2 - m);
    const float lse = __logf(e0 + e1 + e2);
    out[(size_t)n * 3 + 0] = v0 - m - lse;
    out[(size_t)n * 3 + 1] = v1 - m - lse;
    out[(size_t)n * 3 + 2] = v2 - m - lse;
  }
}

extern "C" void kernel_launch(void* const* d_in, const int* in_sizes, int n_in,
                              void* d_out, int out_size, void* d_ws,
                              size_t ws_size, hipStream_t stream) {
  const float* x = (const float*)d_in[0];
  const int* ei = (const int*)d_in[1];  // int32 (JAX x64 disabled)
  const float* Wl1 = (const float*)d_in[2];
  const float* Wr1 = (const float*)d_in[3];
  const float* b1 = (const float*)d_in[4];
  const float* Wl2 = (const float*)d_in[5];
  const float* Wr2 = (const float*)d_in[6];
  const float* b2 = (const float*)d_in[7];
  float* out = (float*)d_out;

  const int N = in_sizes[0] / IN_DIM;
  const int E = in_sizes[1] / 2;
  const int nb1 = (N + SCAN_B - 1) / SCAN_B;
  const int ntiles = (N + 63) / 64;

  int* wsI = (int*)d_ws;
  int* deg_i = wsI;              // [N]  (16B aligned)
  int* row_off = deg_i + N;      // [N]
  int* incl = row_off + N;       // [N]
  int* bsum = incl + N;          // [SCAN_B]
  int* eoff = bsum + SCAN_B;     // [E]
  int* csr_src = eoff + E;       // [E]
  _Float16* wcatT = (_Float16*)(csr_src + E);   // [128*128] f16
  _Float16* xW = wcatT + 128 * 128;             // [N*64] f16
  _Float16* xWr = xW + (size_t)N * HID;         // [N*64] f16
  float* pl = (float*)(xWr + (size_t)N * HID);  // [N*3]
  float* pr = pl + (size_t)N * 3;               // [N*3]

  const int n4 = (N + 3) / 4;
  const int initg = (max(n4, 16384) + 255) / 256;
  init_kernel<<<initg, 256, 0, stream>>>(Wl1, Wr1, wcatT, (int4*)deg_i, n4);
  proj1_count_kernel<<<PB + 512, 256, 0, stream>>>(x, wcatT, xW, xWr, N,
                                                   ntiles, ei, deg_i, eoff, E);
  scan1_kernel<<<nb1, SCAN_B, 0, stream>>>(deg_i, incl, bsum, N);
  scan23_kernel<<<(N + 255) / 256, 256, 0, stream>>>(incl, deg_i, bsum,
                                                     row_off, N);
  fill_kernel<<<(E + 255) / 256, 256, 0, stream>>>(ei, row_off, eoff, csr_src,
                                                   E);
  layer1_kernel<<<ntiles, 256, 0, stream>>>(row_off, deg_i, csr_src, xW, xWr,
                                            b1, Wl2, Wr2, pl, pr, N, ntiles);
  final_kernel<<<(N + 255) / 256, 256, 0, stream>>>(row_off, deg_i, csr_src,
                                                    pl, pr, b2, out, N);
}

// Round 15
// 116.581 us; speedup vs baseline: 1.8514x; 1.1287x over previous
//
#include <hip/hip_runtime.h>
#include <hip/hip_bf16.h>

#define IN_DIM 128
#define HID 64
#define SCAN_B 1024
#define WSTR 136  // f16 LDS row stride (pad: 2-way bank access, free)
#define PB 768    // proj1 blocks inside proj1_count_kernel

using half8 = __attribute__((ext_vector_type(8))) _Float16;
using half2v = __attribute__((ext_vector_type(2))) _Float16;
using f32x4 = __attribute__((ext_vector_type(4))) float;

// ---- init: zero deg_i AND convert [Wl1|Wr1] -> f16 wcatT (fused) ----------
__global__ __launch_bounds__(256) void init_kernel(
    const float* __restrict__ Wl, const float* __restrict__ Wr,
    _Float16* __restrict__ wcatT, int4* __restrict__ deg4, int n4) {
  const int i = blockIdx.x * 256 + threadIdx.x;
  if (i < 16384) {
    const int col = i >> 7;
    const int k = i & 127;
    const float v = (col < 64) ? Wl[k * HID + col] : Wr[k * HID + col - 64];
    wcatT[col * 128 + k] = (_Float16)v;
  }
  if (i < n4) deg4[i] = (int4){0, 0, 0, 0};
}

// ---- proj1 (blocks 0..PB-1) PARALLEL WITH count (blocks PB..) -------------
// proj1: A-fragments loaded DIRECTLY from global x (no LDS stage, no loop
// barriers — R14 counters: VALUBusy 4.9%, latency-bound on the stage chain).
__global__ __launch_bounds__(256) void proj1_count_kernel(
    const float* __restrict__ x, const _Float16* __restrict__ wcatT,
    _Float16* __restrict__ xW, _Float16* __restrict__ xWr, int N, int ntiles,
    const int* __restrict__ ei, int* __restrict__ deg_i,
    int* __restrict__ eoff, int E) {
  const int tx = threadIdx.x;
  if (blockIdx.x >= PB) {
    const int nb = gridDim.x - PB;
    for (int e = (blockIdx.x - PB) * 256 + tx; e < E; e += nb * 256)
      eoff[e] = atomicAdd(&deg_i[ei[E + e]], 1);
    return;
  }
  __shared__ _Float16 wsT[128][WSTR];  // [col][k] 34816 B (only LDS user)

#pragma unroll
  for (int it = 0; it < 8; ++it) {
    const int e8 = it * 256 + tx;
    const int col = e8 >> 4;
    const int k8 = (e8 & 15) * 8;
    *(half8*)&wsT[col][k8] = *(const half8*)&wcatT[col * 128 + k8];
  }

  const int lane = tx & 63;
  const int wv = tx >> 6;
  const int lrow = lane & 15;
  const int g = lane >> 4;
  const float4* x4 = (const float4*)x;

  __syncthreads();

#pragma unroll 1
  for (int tile = blockIdx.x; tile < ntiles; tile += PB) {
    const int n0 = tile * 64;
    const int row = n0 + wv * 16 + lrow;

    f32x4 acc[8];
#pragma unroll
    for (int ct = 0; ct < 8; ++ct) acc[ct] = (f32x4){0.f, 0.f, 0.f, 0.f};

#pragma unroll
    for (int kt = 0; kt < 4; ++kt) {
      half8 a;
      if (row < N) {
        const float4 u = x4[(size_t)row * 32 + kt * 8 + g * 2];
        const float4 v = x4[(size_t)row * 32 + kt * 8 + g * 2 + 1];
        a[0] = (_Float16)u.x; a[1] = (_Float16)u.y;
        a[2] = (_Float16)u.z; a[3] = (_Float16)u.w;
        a[4] = (_Float16)v.x; a[5] = (_Float16)v.y;
        a[6] = (_Float16)v.z; a[7] = (_Float16)v.w;
      } else {
        a = (half8){0, 0, 0, 0, 0, 0, 0, 0};
      }
#pragma unroll
      for (int ct = 0; ct < 8; ++ct) {
        const half8 b = *(const half8*)&wsT[ct * 16 + lrow][kt * 32 + g * 8];
        acc[ct] =
            __builtin_amdgcn_mfma_f32_16x16x32_f16(a, b, acc[ct], 0, 0, 0);
      }
    }

#pragma unroll
    for (int ct = 0; ct < 8; ++ct) {
      const int col = ct * 16 + lrow;
#pragma unroll
      for (int reg = 0; reg < 4; ++reg) {
        const int nn = n0 + wv * 16 + g * 4 + reg;
        if (nn < N) {
          if (col < 64)
            xW[(size_t)nn * HID + col] = (_Float16)acc[ct][reg];
          else
            xWr[(size_t)nn * HID + col - 64] = (_Float16)acc[ct][reg];
        }
      }
    }
  }
}

// ---- scan1: per-chunk inclusive scan of deg (1024-chunks) -----------------
__global__ __launch_bounds__(SCAN_B) void scan1_kernel(
    const int* __restrict__ in, int* __restrict__ incl, int* __restrict__ bsum,
    int n) {
  __shared__ int s[SCAN_B];
  const int t = threadIdx.x;
  const int i = blockIdx.x * SCAN_B + t;
  int v = (i < n) ? in[i] : 0;
  s[t] = v;
  for (int off = 1; off < SCAN_B; off <<= 1) {
    __syncthreads();
    const int a = (t >= off) ? s[t - off] : 0;
    __syncthreads();
    s[t] += a;
  }
  if (i < n) incl[i] = s[t];
  if (t == SCAN_B - 1) bsum[blockIdx.x] = s[t];
}

// ---- scan23: row_off[i] = incl[i] - deg[i] + sum(bsum[0..i>>10)) ----------
__global__ __launch_bounds__(256) void scan23_kernel(
    const int* __restrict__ incl, const int* __restrict__ deg_i,
    const int* __restrict__ bsum, int* __restrict__ row_off, int n) {
  __shared__ int sred[256];
  const int t = threadIdx.x;
  const int chunk = blockIdx.x >> 2;
  sred[t] = (t < chunk) ? bsum[t] : 0;
  __syncthreads();
#pragma unroll
  for (int off = 128; off >= 1; off >>= 1) {
    if (t < off) sred[t] += sred[t + off];
    __syncthreads();
  }
  const int boff = sred[0];
  const int i = blockIdx.x * 256 + t;
  if (i < n) row_off[i] = incl[i] - deg_i[i] + boff;
}

// fill: pos precomputed; atomicExch store avoids per-XCD dirty-line
// amplification (R10 counter evidence: plain scatter stores -> 15x WRITE).
__global__ __launch_bounds__(256) void fill_kernel(
    const int* __restrict__ ei, const int* __restrict__ row_off,
    const int* __restrict__ eoff, int* __restrict__ csr_src, int E) {
  const int e = blockIdx.x * blockDim.x + threadIdx.x;
  if (e < E) {
    const int s = ei[e];
    const int d = ei[E + e];
    atomicExch(&csr_src[row_off[d] + eoff[e]], s);
  }
}

// ---- layer1: gather+relu+proj2 fused. Half-wave per node: lanes 0-31 do
// node 2p, lanes 32-63 node 2p+1 (half2 cols) -> 2 concurrent latency
// chains x 4-deep unroll = 8 outstanding row reads (R14: serial chain). -----
__global__ __launch_bounds__(256) void layer1_kernel(
    const int* __restrict__ row_off, const int* __restrict__ deg_i,
    const int* __restrict__ csr_src, const _Float16* __restrict__ xW,
    const _Float16* __restrict__ xWr, const float* __restrict__ b1,
    const float* __restrict__ Wl2, const float* __restrict__ Wr2,
    float* __restrict__ pl, float* __restrict__ pr, int N, int ntiles) {
  __shared__ _Float16 wlds[16][72];  // [outc][k], outc>=6 zero
  __shared__ _Float16 hlds[64][72];  // [node_local][col]
  const int tx = threadIdx.x;
  for (int i = tx; i < 1024; i += 256) {
    const int c = i >> 6;
    const int k = i & 63;
    float v = 0.f;
    if (c < 3) v = Wl2[k * 3 + c];
    else if (c < 6) v = Wr2[k * 3 + (c - 3)];
    wlds[c][k] = (_Float16)v;
  }
  const int lane = tx & 63;
  const int wv = tx >> 6;
  const int lrow = lane & 15;
  const int g = lane >> 4;
  const int half = lane >> 5;       // 0: node 2p, 1: node 2p+1
  const int c2 = lane & 31;         // half2 column index (cols 2c2, 2c2+1)
  const float2 bb2 = *(const float2*)&b1[2 * c2];
  const half2v* xW2 = (const half2v*)xW;
  const half2v* xWr2 = (const half2v*)xWr;
  __syncthreads();

#pragma unroll 1
  for (int tile = blockIdx.x; tile < ntiles; tile += gridDim.x) {
    const int base = tile * 64;
    // ---- phase 1: 8 node-pairs per wave ----
#pragma unroll 1
    for (int p = 0; p < 8; ++p) {
      const int nl = 2 * p + half;            // node-local 0..15
      const int myN = base + wv * 16 + nl;
      float a0x = 0.f, a0y = 0.f, a1x = 0.f, a1y = 0.f;
      float a2x = 0.f, a2y = 0.f, a3x = 0.f, a3y = 0.f;
      int start = 0, dg = 0;
      if (myN < N) {
        start = row_off[myN];
        dg = deg_i[myN];
      }
      int r = 0;
      for (; r + 3 < dg; r += 4) {
        const int s0 = csr_src[start + r];
        const int s1 = csr_src[start + r + 1];
        const int s2 = csr_src[start + r + 2];
        const int s3 = csr_src[start + r + 3];
        const half2v v0 = xW2[(size_t)s0 * 32 + c2];
        const half2v v1 = xW2[(size_t)s1 * 32 + c2];
        const half2v v2 = xW2[(size_t)s2 * 32 + c2];
        const half2v v3 = xW2[(size_t)s3 * 32 + c2];
        a0x += (float)v0.x; a0y += (float)v0.y;
        a1x += (float)v1.x; a1y += (float)v1.y;
        a2x += (float)v2.x; a2y += (float)v2.y;
        a3x += (float)v3.x; a3y += (float)v3.y;
      }
      for (; r < dg; ++r) {
        const half2v v0 = xW2[(size_t)csr_src[start + r] * 32 + c2];
        a0x += (float)v0.x; a0y += (float)v0.y;
      }
      const float dinv = 1.0f / fmaxf((float)dg, 1.0f);
      half2v wr = {0, 0};
      if (myN < N) wr = xWr2[(size_t)myN * 32 + c2];
      const float hx =
          fmaxf(((a0x + a1x) + (a2x + a3x)) * dinv + (float)wr.x + bb2.x, 0.f);
      const float hy =
          fmaxf(((a0y + a1y) + (a2y + a3y)) * dinv + (float)wr.y + bb2.y, 0.f);
      half2v hv;
      hv.x = (_Float16)hx;
      hv.y = (_Float16)hy;
      *(half2v*)&hlds[wv * 16 + nl][2 * c2] = hv;
    }
    __syncthreads();
    // ---- phase 2: 64->6 projection off LDS (2 MFMA per wave) ----
    f32x4 acc = (f32x4){0.f, 0.f, 0.f, 0.f};
#pragma unroll
    for (int kt = 0; kt < 2; ++kt) {
      const half8 a = *(const half8*)&hlds[wv * 16 + lrow][kt * 32 + g * 8];
      const half8 b = *(const half8*)&wlds[lrow][kt * 32 + g * 8];
      acc = __builtin_amdgcn_mfma_f32_16x16x32_f16(a, b, acc, 0, 0, 0);
    }
    if (lrow < 6) {
#pragma unroll
      for (int reg = 0; reg < 4; ++reg) {
        const int n = base + wv * 16 + g * 4 + reg;
        if (n < N) {
          if (lrow < 3)
            pl[(size_t)n * 3 + lrow] = acc[reg];
          else
            pr[(size_t)n * 3 + lrow - 3] = acc[reg];
        }
      }
    }
    __syncthreads();  // hlds reads done before next tile's writes
  }
}

// ---- final: gather pl over neighbors, log_softmax (2-row unroll) ----------
__global__ __launch_bounds__(256) void final_kernel(
    const int* __restrict__ row_off, const int* __restrict__ deg_i,
    const int* __restrict__ csr_src, const float* __restrict__ pl,
    const float* __restrict__ pr, const float* __restrict__ b2,
    float* __restrict__ out, int N) {
  const int stride = gridDim.x * blockDim.x;
  const float b20 = b2[0], b21 = b2[1], b22 = b2[2];
  for (int n = blockIdx.x * blockDim.x + threadIdx.x; n < N; n += stride) {
    const int start = row_off[n];
    const int dg = deg_i[n];
    float s0 = 0.f, s1 = 0.f, s2 = 0.f;
    float t0 = 0.f, t1 = 0.f, t2 = 0.f;
    int r = 0;
    for (; r + 1 < dg; r += 2) {
      const int sa = csr_src[start + r];
      const int sb = csr_src[start + r + 1];
      s0 += pl[(size_t)sa * 3 + 0];
      s1 += pl[(size_t)sa * 3 + 1];
      s2 += pl[(size_t)sa * 3 + 2];
      t0 += pl[(size_t)sb * 3 + 0];
      t1 += pl[(size_t)sb * 3 + 1];
      t2 += pl[(size_t)sb * 3 + 2];
    }
    if (r < dg) {
      const int sa = csr_src[start + r];
      s0 += pl[(size_t)sa * 3 + 0];
      s1 += pl[(size_t)sa * 3 + 1];
      s2 += pl[(size_t)sa * 3 + 2];
    }
    const float dinv = 1.0f / fmaxf((float)dg, 1.0f);
    const float v0 = (s0 + t0) * dinv + pr[(size_t)n * 3 + 0] + b20;
    const float v1 = (s1 + t1) * dinv + pr[(size_t)n * 3 + 1] + b21;
    const float v2 = (s2 + t2) * dinv + pr[(size_t)n * 3 + 2] + b22;
    const float m = fmaxf(fmaxf(v0, v1), v2);
    const float e0 = __expf(v0 - m), e1 = __expf(v1 - m), e2 = __expf(v2 - m);
    const float lse = __logf(e0 + e1 + e2);
    out[(size_t)n * 3 + 0] = v0 - m - lse;
    out[(size_t)n * 3 + 1] = v1 - m - lse;
    out[(size_t)n * 3 + 2] = v2 - m - lse;
  }
}

extern "C" void kernel_launch(void* const* d_in, const int* in_sizes, int n_in,
                              void* d_out, int out_size, void* d_ws,
                              size_t ws_size, hipStream_t stream) {
  const float* x = (const float*)d_in[0];
  const int* ei = (const int*)d_in[1];  // int32 (JAX x64 disabled)
  const float* Wl1 = (const float*)d_in[2];
  const float* Wr1 = (const float*)d_in[3];
  const float* b1 = (const float*)d_in[4];
  const float* Wl2 = (const float*)d_in[5];
  const float* Wr2 = (const float*)d_in[6];
  const float* b2 = (const float*)d_in[7];
  float* out = (float*)d_out;

  const int N = in_sizes[0] / IN_DIM;
  const int E = in_sizes[1] / 2;
  const int nb1 = (N + SCAN_B - 1) / SCAN_B;
  const int ntiles = (N + 63) / 64;

  int* wsI = (int*)d_ws;
  int* deg_i = wsI;              // [N]  (16B aligned)
  int* row_off = deg_i + N;      // [N]
  int* incl = row_off + N;       // [N]
  int* bsum = incl + N;          // [SCAN_B]
  int* eoff = bsum + SCAN_B;     // [E]
  int* csr_src = eoff + E;       // [E]
  _Float16* wcatT = (_Float16*)(csr_src + E);   // [128*128] f16
  _Float16* xW = wcatT + 128 * 128;             // [N*64] f16
  _Float16* xWr = xW + (size_t)N * HID;         // [N*64] f16
  float* pl = (float*)(xWr + (size_t)N * HID);  // [N*3]
  float* pr = pl + (size_t)N * 3;               // [N*3]

  const int n4 = (N + 3) / 4;
  const int initg = (max(n4, 16384) + 255) / 256;
  init_kernel<<<initg, 256, 0, stream>>>(Wl1, Wr1, wcatT, (int4*)deg_i, n4);
  proj1_count_kernel<<<PB + 512, 256, 0, stream>>>(x, wcatT, xW, xWr, N,
                                                   ntiles, ei, deg_i, eoff, E);
  scan1_kernel<<<nb1, SCAN_B, 0, stream>>>(deg_i, incl, bsum, N);
  scan23_kernel<<<(N + 255) / 256, 256, 0, stream>>>(incl, deg_i, bsum,
                                                     row_off, N);
  fill_kernel<<<(E + 255) / 256, 256, 0, stream>>>(ei, row_off, eoff, csr_src,
                                                   E);
  layer1_kernel<<<ntiles, 256, 0, stream>>>(row_off, deg_i, csr_src, xW, xWr,
                                            b1, Wl2, Wr2, pl, pr, N, ntiles);
  final_kernel<<<(N + 255) / 256, 256, 0, stream>>>(row_off, deg_i, csr_src,
                                                    pl, pr, b2, out, N);
}